// Round 7
// baseline (540.430 us; speedup 1.0000x reference)
//
#include <hip/hip_runtime.h>
#include <math.h>

typedef float f4 __attribute__((ext_vector_type(4)));
typedef float f32x4 __attribute__((ext_vector_type(4)));
typedef short bf16x8 __attribute__((ext_vector_type(8)));
typedef unsigned int u32x4 __attribute__((ext_vector_type(4)));
typedef unsigned int u32x2 __attribute__((ext_vector_type(2)));
typedef unsigned short u16;
typedef unsigned int u32;

#define D_MODEL 1024
#define N_HEADS 16
#define D_HEAD  64
#define N_BINS  64
#define D_LAT   8

// ---------------------------------------------------------------------------
// bf16 split helpers (RTNE)
// ---------------------------------------------------------------------------
__device__ __forceinline__ unsigned short bf16_rtne(float f) {
    unsigned int u = __builtin_bit_cast(unsigned int, f);
    u += 0x7FFFu + ((u >> 16) & 1u);
    return (unsigned short)(u >> 16);
}
__device__ __forceinline__ float bf16_to_f32(unsigned short h) {
    unsigned int u = ((unsigned int)h) << 16;
    return __builtin_bit_cast(float, u);
}
__device__ __forceinline__ u32 pack_hl(float v) {
    unsigned short h = bf16_rtne(v);
    unsigned short l = bf16_rtne(v - bf16_to_f32(h));
    return (u32)h | ((u32)l << 16);
}
// unpack 8 consecutive packed (hi | lo<<16) u32 -> hi-frag, lo-frag
__device__ __forceinline__ void unpack8(const u32* p, bf16x8& hf, bf16x8& lf) {
    u32x4 r0 = *(const u32x4*)p;
    u32x4 r1 = *(const u32x4*)(p + 4);
    u32x4 hv, lv;
    hv[0] = (r0[0] & 0xffffu) | (r0[1] << 16);  lv[0] = (r0[0] >> 16) | (r0[1] & 0xffff0000u);
    hv[1] = (r0[2] & 0xffffu) | (r0[3] << 16);  lv[1] = (r0[2] >> 16) | (r0[3] & 0xffff0000u);
    hv[2] = (r1[0] & 0xffffu) | (r1[1] << 16);  lv[2] = (r1[0] >> 16) | (r1[1] & 0xffff0000u);
    hv[3] = (r1[2] & 0xffffu) | (r1[3] << 16);  lv[3] = (r1[2] >> 16) | (r1[3] & 0xffff0000u);
    hf = __builtin_bit_cast(bf16x8, hv);
    lf = __builtin_bit_cast(bf16x8, lv);
}

// fp32 -> (hi, lo) bf16 buffers, 8 elems/thread
__global__ __launch_bounds__(256)
void split_bf16x2(const float* __restrict__ in, unsigned short* __restrict__ hi,
                  unsigned short* __restrict__ lo, int n8)
{
    int i = blockIdx.x * 256 + threadIdx.x;
    if (i >= n8) return;
    const f4* inp = (const f4*)in;
    f4 a = inp[2 * i];
    f4 b = inp[2 * i + 1];
    unsigned short hs[8], ls[8];
#pragma unroll
    for (int j = 0; j < 8; j++) {
        float v = (j < 4) ? a[j] : b[j - 4];
        unsigned short h = bf16_rtne(v);
        hs[j] = h;
        ls[j] = bf16_rtne(v - bf16_to_f32(h));
    }
    u32x4 ho, lv;
#pragma unroll
    for (int j = 0; j < 4; j++) {
        ho[j] = (unsigned int)hs[2 * j] | ((unsigned int)hs[2 * j + 1] << 16);
        lv[j] = (unsigned int)ls[2 * j] | ((unsigned int)ls[2 * j + 1] << 16);
    }
    ((u32x4*)hi)[i] = ho;
    ((u32x4*)lo)[i] = lv;
}

// all four weight matrices -> one concat hi/lo buffer (order q,k,v,o)
__global__ __launch_bounds__(256)
void split4_w(const float* __restrict__ w0, const float* __restrict__ w1,
              const float* __restrict__ w2, const float* __restrict__ w3,
              unsigned short* __restrict__ hi, unsigned short* __restrict__ lo)
{
    const int which = blockIdx.y;
    const float* in = (which == 0) ? w0 : (which == 1) ? w1 : (which == 2) ? w2 : w3;
    int i = blockIdx.x * 256 + threadIdx.x;          // item of 8 elems
    const f4* inp = (const f4*)in;
    f4 a = inp[2 * i];
    f4 b = inp[2 * i + 1];
    unsigned short hs[8], ls[8];
#pragma unroll
    for (int j = 0; j < 8; j++) {
        float v = (j < 4) ? a[j] : b[j - 4];
        unsigned short h = bf16_rtne(v);
        hs[j] = h;
        ls[j] = bf16_rtne(v - bf16_to_f32(h));
    }
    u32x4 ho, lv;
#pragma unroll
    for (int j = 0; j < 4; j++) {
        ho[j] = (unsigned int)hs[2 * j] | ((unsigned int)hs[2 * j + 1] << 16);
        lv[j] = (unsigned int)ls[2 * j] | ((unsigned int)ls[2 * j + 1] << 16);
    }
    size_t off = (size_t)which * (D_MODEL * D_MODEL / 8);
    ((u32x4*)hi)[off + i] = ho;
    ((u32x4*)lo)[off + i] = lv;
}

// ---------------------------------------------------------------------------
// Split-bf16 MFMA GEMM (NT): C[M,N] = (Ahi+Alo)[M,K] * (Whi+Wlo)[N,K]^T + bias
// 256x256 tile, BK=32, 512 threads (8 waves as 2Mx4N, each 128x64 out),
// double-buffered 128KB LDS via global_load_lds(16B), conflict-free
// (r>>1)&3 chunk-XOR swizzle (bank-conflict = 0, verified r6).
// NEW (T3+T4+T5): 4-phase schedule per K-tile. Each phase: {ds_read this
// phase's fragments | issue 2 global_load_lds for tile t+1 | setprio(1) |
// 24-MFMA cluster | setprio(0) | raw s_barrier}. Single vmcnt(0)+barrier
// at the tile flip (the only true sync point — same memory semantics as
// the passing r6 __syncthreads version; raw barriers avoid the compiler's
// full vmcnt-drain before every barrier).
// ---------------------------------------------------------------------------
__device__ __forceinline__ void glds16(const unsigned short* g, unsigned short* l) {
    __builtin_amdgcn_global_load_lds((const __attribute__((address_space(1))) void*)g,
                                     (__attribute__((address_space(3))) void*)l,
                                     16, 0, 0);
}

#define MFMA3(ACC, AH, AL, BH, BL) do {                                        \
    f32x4 _a = (ACC);                                                          \
    _a = __builtin_amdgcn_mfma_f32_16x16x32_bf16((AH), (BH), _a, 0, 0, 0);     \
    _a = __builtin_amdgcn_mfma_f32_16x16x32_bf16((AH), (BL), _a, 0, 0, 0);     \
    _a = __builtin_amdgcn_mfma_f32_16x16x32_bf16((AL), (BH), _a, 0, 0, 0);     \
    (ACC) = _a;                                                                \
} while (0)

template<bool SPLIT>
__global__ __launch_bounds__(512)
void gemm_bf16x2_nt(const unsigned short* __restrict__ Ahi, const unsigned short* __restrict__ Alo,
                    const unsigned short* __restrict__ Bhi, const unsigned short* __restrict__ Blo,
                    const float* __restrict__ bias, float* __restrict__ C,
                    unsigned short* __restrict__ Chi, unsigned short* __restrict__ Clo,
                    int M, int N, int K)
{
    __shared__ unsigned short lds[2][4][8192];   // [dbuf][Ahi,Alo,Bhi,Blo][256r x 32k]

    const int tid  = threadIdx.x;
    const int lane = tid & 63;
    const int w    = tid >> 6;
    const int wm   = w >> 2;         // 0..1
    const int wn   = w & 3;          // 0..3
    const int bm   = blockIdx.x * 256;
    const int bn   = blockIdx.y * 256;

    // staging: seg s covers rows [s*16,s*16+16); wave w handles s = i*8+w.
    // row-within-seg = lane>>2 => row bits 1..2 = (lane>>3)&3.
    const int schunk = (lane & 3) ^ ((lane >> 3) & 3);
    size_t gA[2], gB[2];
    int    seg[2];
#pragma unroll
    for (int i = 0; i < 2; i++) {
        int s = i * 8 + w;
        int r = s * 16 + (lane >> 2);
        gA[i]  = (size_t)(bm + r) * K + schunk * 8;
        gB[i]  = (size_t)(bn + r) * K + schunk * 8;
        seg[i] = s * 512;            // ushort offset of 1KB segment
    }

    // fragment read: row = base16 + (lane&15); slot = (lane>>4) ^ ((row>>1)&3)
    const int koff  = ((lane >> 4) ^ ((lane >> 1) & 3)) * 8;
    const int abase = (wm * 128 + (lane & 15)) * 32 + koff;
    const int bbase = (wn * 64  + (lane & 15)) * 32 + koff;

    f32x4 acc[8][4];
#pragma unroll
    for (int i = 0; i < 8; i++)
#pragma unroll
        for (int j = 0; j < 4; j++) acc[i][j] = (f32x4){0.f, 0.f, 0.f, 0.f};

    // prologue: stage tile 0, drain, sync
#pragma unroll
    for (int i = 0; i < 2; i++) {
        glds16(Ahi + gA[i], &lds[0][0][seg[i]]);
        glds16(Alo + gA[i], &lds[0][1][seg[i]]);
        glds16(Bhi + gB[i], &lds[0][2][seg[i]]);
        glds16(Blo + gB[i], &lds[0][3][seg[i]]);
    }
    asm volatile("s_waitcnt vmcnt(0)" ::: "memory");
    __builtin_amdgcn_s_barrier();

    const int nt = K / 32;
    for (int t = 0; t < nt; t++) {
        const int cur = t & 1;
        const int nxt = cur ^ 1;
        const bool pre = (t + 1 < nt);
        const int kt = (t + 1) * 32;

        bf16x8 a0h[4], a0l[4], a1h[4], a1l[4];
        bf16x8 b0h[2], b0l[2], b1h[2], b1l[2];

        // ---------- phase 0: read A0..3 + B0..1, stage Ahi, MFMA q00 ----------
#pragma unroll
        for (int i = 0; i < 4; i++) {
            a0h[i] = *(const bf16x8*)&lds[cur][0][abase + i * 512];
            a0l[i] = *(const bf16x8*)&lds[cur][1][abase + i * 512];
        }
#pragma unroll
        for (int j = 0; j < 2; j++) {
            b0h[j] = *(const bf16x8*)&lds[cur][2][bbase + j * 512];
            b0l[j] = *(const bf16x8*)&lds[cur][3][bbase + j * 512];
        }
        if (pre) {
            glds16(Ahi + gA[0] + kt, &lds[nxt][0][seg[0]]);
            glds16(Ahi + gA[1] + kt, &lds[nxt][0][seg[1]]);
        }
        __builtin_amdgcn_s_setprio(1);
#pragma unroll
        for (int i = 0; i < 4; i++)
#pragma unroll
            for (int j = 0; j < 2; j++)
                MFMA3(acc[i][j], a0h[i], a0l[i], b0h[j], b0l[j]);
        __builtin_amdgcn_s_setprio(0);
        __builtin_amdgcn_s_barrier();

        // ---------- phase 1: read B2..3, stage Alo, MFMA q01 ----------
#pragma unroll
        for (int j = 0; j < 2; j++) {
            b1h[j] = *(const bf16x8*)&lds[cur][2][bbase + (2 + j) * 512];
            b1l[j] = *(const bf16x8*)&lds[cur][3][bbase + (2 + j) * 512];
        }
        if (pre) {
            glds16(Alo + gA[0] + kt, &lds[nxt][1][seg[0]]);
            glds16(Alo + gA[1] + kt, &lds[nxt][1][seg[1]]);
        }
        __builtin_amdgcn_s_setprio(1);
#pragma unroll
        for (int i = 0; i < 4; i++)
#pragma unroll
            for (int j = 0; j < 2; j++)
                MFMA3(acc[i][2 + j], a0h[i], a0l[i], b1h[j], b1l[j]);
        __builtin_amdgcn_s_setprio(0);
        __builtin_amdgcn_s_barrier();

        // ---------- phase 2: read A4..7, stage Bhi, MFMA q10 ----------
#pragma unroll
        for (int i = 0; i < 4; i++) {
            a1h[i] = *(const bf16x8*)&lds[cur][0][abase + (4 + i) * 512];
            a1l[i] = *(const bf16x8*)&lds[cur][1][abase + (4 + i) * 512];
        }
        if (pre) {
            glds16(Bhi + gB[0] + kt, &lds[nxt][2][seg[0]]);
            glds16(Bhi + gB[1] + kt, &lds[nxt][2][seg[1]]);
        }
        __builtin_amdgcn_s_setprio(1);
#pragma unroll
        for (int i = 0; i < 4; i++)
#pragma unroll
            for (int j = 0; j < 2; j++)
                MFMA3(acc[4 + i][j], a1h[i], a1l[i], b0h[j], b0l[j]);
        __builtin_amdgcn_s_setprio(0);
        __builtin_amdgcn_s_barrier();

        // ---------- phase 3: stage Blo, MFMA q11, flip ----------
        if (pre) {
            glds16(Blo + gB[0] + kt, &lds[nxt][3][seg[0]]);
            glds16(Blo + gB[1] + kt, &lds[nxt][3][seg[1]]);
        }
        __builtin_amdgcn_s_setprio(1);
#pragma unroll
        for (int i = 0; i < 4; i++)
#pragma unroll
            for (int j = 0; j < 2; j++)
                MFMA3(acc[4 + i][2 + j], a1h[i], a1l[i], b1h[j], b1l[j]);
        __builtin_amdgcn_s_setprio(0);
        // flip seam: own stage loads landed + all waves past their drain
        asm volatile("s_waitcnt vmcnt(0)" ::: "memory");
        __builtin_amdgcn_s_barrier();
    }

    // epilogue: C/D layout col = lane&15, row = (lane>>4)*4 + e
    const int rb = bm + wm * 128;
    const int cb = bn + wn * 64;
    float bv[4];
#pragma unroll
    for (int fn = 0; fn < 4; fn++) bv[fn] = bias[cb + fn * 16 + (lane & 15)];
#pragma unroll
    for (int fm = 0; fm < 8; fm++)
#pragma unroll
        for (int e = 0; e < 4; e++) {
            size_t row = (size_t)(rb + fm * 16 + (lane >> 4) * 4 + e);
            if constexpr (SPLIT) {
#pragma unroll
                for (int fn = 0; fn < 4; fn++) {
                    float v = acc[fm][fn][e] + bv[fn];
                    unsigned short h = bf16_rtne(v);
                    Chi[row * N + cb + fn * 16 + (lane & 15)] = h;
                    Clo[row * N + cb + fn * 16 + (lane & 15)] = bf16_rtne(v - bf16_to_f32(h));
                }
            } else {
                float* cp = &C[row * N];
#pragma unroll
                for (int fn = 0; fn < 4; fn++)
                    cp[cb + fn * 16 + (lane & 15)] = acc[fm][fn][e] + bv[fn];
            }
        }
}

// ---------------------------------------------------------------------------
// Bin assignment + soft aggregation (MFMA aggregation; unchanged from r6).
// ---------------------------------------------------------------------------
__global__ __launch_bounds__(256)
void bin_assign_agg(const float* __restrict__ Kbuf, const float* __restrict__ Vbuf,
                    const float* __restrict__ W_bin, const float* __restrict__ proto,
                    const float* __restrict__ log_tau,
                    float* __restrict__ partials, int B, int S)
{
    __shared__ __attribute__((aligned(16))) float Wb[8][64];
    __shared__ __attribute__((aligned(16))) float Prt[8][64];
    __shared__ __attribute__((aligned(16))) float zsm[64][8];
    __shared__ __attribute__((aligned(16))) float Kt[64][68];
    __shared__ __attribute__((aligned(16))) u32 KT32[64][68];   // [d][s] packed hi|lo
    __shared__ __attribute__((aligned(16))) u32 VT32[64][68];
    __shared__ __attribute__((aligned(16))) u32 P32T[64][68];   // [n][s] packed hi|lo

    const int bh = blockIdx.x;
    const int h  = bh & (N_HEADS - 1);
    const int b  = bh >> 4;
    const int chunk = blockIdx.y;
    const int CH = gridDim.y;
    const int tid = threadIdx.x;
    const int lane = tid & 63;
    const int w = tid >> 6;

    if (tid < 128) {
        ((f4*)&Wb[0][0])[tid] = ((const f4*)W_bin)[tid];
    } else {
        int t = tid - 128;
        f4 p = ((const f4*)(proto + (size_t)h * N_BINS * D_LAT))[t];
        int n = t >> 1, l4 = (t & 1) * 4;
        Prt[l4 + 0][n] = p[0];
        Prt[l4 + 1][n] = p[1];
        Prt[l4 + 2][n] = p[2];
        Prt[l4 + 3][n] = p[3];
    }
    const float tau   = fmaxf(expf(log_tau[h]), 1e-3f);
    const float scale = 1.0f / (tau + 1e-8f);

    const int row = tid >> 2, sub = tid & 3;   // softmax: 4 lanes per key row
    const int lr = lane & 15, lc = lane >> 4;  // MFMA fragment indices
    const int mat = w >> 1;                    // 0 = K, 1 = V
    const int fn0 = (w & 1) * 2;               // d fragment pair

    f32x4 acc[4][2];
    f4 cntv[4];
#pragma unroll
    for (int i = 0; i < 4; i++) {
        cntv[i] = (f4){0.f, 0.f, 0.f, 0.f};
        acc[i][0] = (f32x4){0.f, 0.f, 0.f, 0.f};
        acc[i][1] = (f32x4){0.f, 0.f, 0.f, 0.f};
    }

    const int SC = S / CH;
    const int s_base = chunk * SC;

    for (int s0 = 0; s0 < SC; s0 += 64) {
        __syncthreads();   // previous chunk's MFMA reads done before restage
#pragma unroll
        for (int q = 0; q < 2; q++) {
            int item = tid + 256 * q;       // 0..511
            int rp = item >> 4;             // 0..31
            int dc = item & 15;
            int r0 = rp * 2;
            size_t gi = ((size_t)(b * S + s_base + s0 + r0)) * D_MODEL + h * D_HEAD + dc * 4;
            f4 k0 = *(const f4*)&Kbuf[gi];
            f4 k1 = *(const f4*)&Kbuf[gi + D_MODEL];
            f4 v0 = *(const f4*)&Vbuf[gi];
            f4 v1 = *(const f4*)&Vbuf[gi + D_MODEL];
            *(f4*)&Kt[r0][dc * 4]     = k0;
            *(f4*)&Kt[r0 + 1][dc * 4] = k1;
#pragma unroll
            for (int j = 0; j < 4; j++) {
                int d = dc * 4 + j;
                *(u32x2*)&KT32[d][r0] = (u32x2){pack_hl(k0[j]), pack_hl(k1[j])};
                *(u32x2*)&VT32[d][r0] = (u32x2){pack_hl(v0[j]), pack_hl(v1[j])};
            }
        }
        __syncthreads();

        {
            const int l0 = sub * 2;
            f4 z0 = {0.f, 0.f, 0.f, 0.f}, z1 = {0.f, 0.f, 0.f, 0.f};
#pragma unroll
            for (int d4 = 0; d4 < 16; d4++) {
                f4 kv = *(const f4*)&Kt[row][d4 * 4];
                f4 w0 = *(const f4*)&Wb[l0][d4 * 4];
                f4 w1 = *(const f4*)&Wb[l0 + 1][d4 * 4];
                z0 += kv * w0;
                z1 += kv * w1;
            }
            zsm[row][l0]     = z0[0] + z0[1] + z0[2] + z0[3];
            zsm[row][l0 + 1] = z1[0] + z1[1] + z1[2] + z1[3];
        }
        __syncthreads();

        {
            float zr[8];
#pragma unroll
            for (int l = 0; l < 8; l++) zr[l] = zsm[row][l];
            f4 lg[4];
#pragma unroll
            for (int q = 0; q < 4; q++) lg[q] = (f4){0.f, 0.f, 0.f, 0.f};
#pragma unroll
            for (int l = 0; l < 8; l++) {
                float zv = zr[l];
#pragma unroll
                for (int q = 0; q < 4; q++) {
                    f4 pr = *(const f4*)&Prt[l][sub * 16 + q * 4];
                    lg[q] += zv * pr;
                }
            }
            float mx = -1e30f;
#pragma unroll
            for (int q = 0; q < 4; q++) {
                lg[q] *= scale;
                mx = fmaxf(mx, fmaxf(fmaxf(lg[q][0], lg[q][1]), fmaxf(lg[q][2], lg[q][3])));
            }
            mx = fmaxf(mx, __shfl_xor(mx, 1));
            mx = fmaxf(mx, __shfl_xor(mx, 2));
            float sum = 0.f;
            f4 pv[4];
#pragma unroll
            for (int q = 0; q < 4; q++) {
#pragma unroll
                for (int e = 0; e < 4; e++) {
                    float ev = expf(lg[q][e] - mx);
                    pv[q][e] = ev;
                    sum += ev;
                }
            }
            sum += __shfl_xor(sum, 1);
            sum += __shfl_xor(sum, 2);
            float inv = 1.0f / sum;
#pragma unroll
            for (int q = 0; q < 4; q++) {
                pv[q] *= inv;
                cntv[q] += pv[q];
#pragma unroll
                for (int e = 0; e < 4; e++)
                    P32T[sub * 16 + q * 4 + e][row] = pack_hl(pv[q][e]);
            }
        }
        __syncthreads();

#pragma unroll
        for (int ks = 0; ks < 2; ks++) {
            bf16x8 pah[4], pal[4];
#pragma unroll
            for (int fm = 0; fm < 4; fm++)
                unpack8(&P32T[fm * 16 + lr][ks * 32 + lc * 8], pah[fm], pal[fm]);
#pragma unroll
            for (int fnL = 0; fnL < 2; fnL++) {
                int dr = (fn0 + fnL) * 16 + lr;
                bf16x8 bhf, blf;
                const u32* bp = mat ? &VT32[dr][ks * 32 + lc * 8]
                                    : &KT32[dr][ks * 32 + lc * 8];
                unpack8(bp, bhf, blf);
#pragma unroll
                for (int fm = 0; fm < 4; fm++) {
                    f32x4 a = acc[fm][fnL];
                    a = __builtin_amdgcn_mfma_f32_16x16x32_bf16(pah[fm], bhf, a, 0, 0, 0);
                    a = __builtin_amdgcn_mfma_f32_16x16x32_bf16(pah[fm], blf, a, 0, 0, 0);
                    a = __builtin_amdgcn_mfma_f32_16x16x32_bf16(pal[fm], bhf, a, 0, 0, 0);
                    acc[fm][fnL] = a;
                }
            }
        }
    }

#pragma unroll
    for (int q = 0; q < 4; q++)
#pragma unroll
        for (int e = 0; e < 4; e++) {
            float c = cntv[q][e];
            c += __shfl_xor(c, 4);
            c += __shfl_xor(c, 8);
            c += __shfl_xor(c, 16);
            c += __shfl_xor(c, 32);
            cntv[q][e] = c;
        }

    float* base = partials + ((size_t)bh * CH + chunk) * 8448;
#pragma unroll
    for (int fm = 0; fm < 4; fm++)
#pragma unroll
        for (int fnL = 0; fnL < 2; fnL++)
#pragma unroll
            for (int e = 0; e < 4; e++) {
                int n = fm * 16 + lc * 4 + e;
                int d = (fn0 + fnL) * 16 + lr;
                base[mat * 4096 + (size_t)n * 64 + d] = acc[fm][fnL][e];
            }
    if ((lane >> 2) == 0) {   // lanes 0..3, sub = lane
#pragma unroll
        for (int q = 0; q < 4; q++)
#pragma unroll
            for (int e = 0; e < 4; e++)
                base[8192 + w * 64 + sub * 16 + q * 4 + e] = cntv[q][e];
    }
}

// ---------------------------------------------------------------------------
// Reduce partials -> bf16 hi/lo K_binned [bh][n][d] and V_binned^T [bh][d][n].
// FAITHFUL to reference broadcast bug: feature d divided by counts[d].
// ---------------------------------------------------------------------------
__global__ __launch_bounds__(256)
void bin_reduce(const float* __restrict__ partials,
                u16* __restrict__ Kbh, u16* __restrict__ Kbl,
                u16* __restrict__ Vth, u16* __restrict__ Vtl, int CH)
{
    const int bh = blockIdx.x;
    const int tid = threadIdx.x;
    __shared__ float inv_cnt[64];
    const float* base = partials + (size_t)bh * CH * 8448;
    if (tid < 64) {
        float c = 0.f;
        for (int ch = 0; ch < CH; ch++)
#pragma unroll
            for (int ww = 0; ww < 4; ww++)
                c += base[(size_t)ch * 8448 + 8192 + ww * 64 + tid];
        inv_cnt[tid] = 1.0f / (c + 1e-6f);
    }
    __syncthreads();
    for (int idx = tid; idx < 4096; idx += 256) {
        float k = 0.f, v = 0.f;
        for (int ch = 0; ch < CH; ch++) {
            const float* p = base + (size_t)ch * 8448;
            k += p[idx];
            v += p[4096 + idx];
        }
        float ic = inv_cnt[idx & 63];   // divide by count of FEATURE index d
        k *= ic;
        v *= ic;
        int n = idx >> 6, d = idx & 63;
        u16 kh = bf16_rtne(k);
        Kbh[(size_t)bh * 4096 + idx] = kh;
        Kbl[(size_t)bh * 4096 + idx] = bf16_rtne(k - bf16_to_f32(kh));
        u16 vh = bf16_rtne(v);
        size_t ti = (size_t)bh * 4096 + (size_t)d * 64 + n;   // transposed
        Vth[ti] = vh;
        Vtl[ti] = bf16_rtne(v - bf16_to_f32(vh));
    }
}

// ---------------------------------------------------------------------------
// Bin attention via bf16x2 MFMA (unchanged, passing).
// ---------------------------------------------------------------------------
__global__ __launch_bounds__(256)
void bin_attn_mfma(const u16* __restrict__ Qhi, const u16* __restrict__ Qlo,
                   const u16* __restrict__ Kbh, const u16* __restrict__ Kbl,
                   const u16* __restrict__ Vth, const u16* __restrict__ Vtl,
                   u16* __restrict__ ctx_hi, u16* __restrict__ ctx_lo,
                   int B, int S)
{
    __shared__ unsigned int P32[4][64][68];

    const int bh = blockIdx.x;
    const int h  = bh & (N_HEADS - 1);
    const int b  = bh >> 4;
    const int tid = threadIdx.x;
    const int l  = tid & 63;
    const int w  = tid >> 6;
    const int s0 = blockIdx.y * 256 + w * 64;

    const int lr = l & 15;
    const int lc = l >> 4;

    const size_t qoff  = ((size_t)(b * S + s0 + lr)) * D_MODEL + h * D_HEAD + lc * 8;
    const size_t kboff = (size_t)bh * 4096 + (size_t)lr * 64 + lc * 8;

    f32x4 acc[4][4];
#pragma unroll
    for (int i = 0; i < 4; i++)
#pragma unroll
        for (int j = 0; j < 4; j++) acc[i][j] = (f32x4){0.f, 0.f, 0.f, 0.f};

#pragma unroll
    for (int ks = 0; ks < 2; ks++) {
        bf16x8 qh[4], ql[4], kh[4], kl[4];
#pragma unroll
        for (int f = 0; f < 4; f++) {
            qh[f] = *(const bf16x8*)(Qhi + qoff + f * 16 * D_MODEL + ks * 32);
            ql[f] = *(const bf16x8*)(Qlo + qoff + f * 16 * D_MODEL + ks * 32);
            kh[f] = *(const bf16x8*)(Kbh + kboff + f * 1024 + ks * 32);
            kl[f] = *(const bf16x8*)(Kbl + kboff + f * 1024 + ks * 32);
        }
#pragma unroll
        for (int fm = 0; fm < 4; fm++)
#pragma unroll
            for (int fn = 0; fn < 4; fn++) {
                acc[fm][fn] = __builtin_amdgcn_mfma_f32_16x16x32_bf16(qh[fm], kh[fn], acc[fm][fn], 0, 0, 0);
                acc[fm][fn] = __builtin_amdgcn_mfma_f32_16x16x32_bf16(qh[fm], kl[fn], acc[fm][fn], 0, 0, 0);
                acc[fm][fn] = __builtin_amdgcn_mfma_f32_16x16x32_bf16(ql[fm], kh[fn], acc[fm][fn], 0, 0, 0);
            }
    }

#pragma unroll
    for (int fm = 0; fm < 4; fm++) {
#pragma unroll
        for (int e = 0; e < 4; e++) {
            float v0 = acc[fm][0][e] * 0.125f;
            float v1 = acc[fm][1][e] * 0.125f;
            float v2 = acc[fm][2][e] * 0.125f;
            float v3 = acc[fm][3][e] * 0.125f;
            float mx = fmaxf(fmaxf(v0, v1), fmaxf(v2, v3));
            mx = fmaxf(mx, __shfl_xor(mx, 1));
            mx = fmaxf(mx, __shfl_xor(mx, 2));
            mx = fmaxf(mx, __shfl_xor(mx, 4));
            mx = fmaxf(mx, __shfl_xor(mx, 8));
            float e0 = expf(v0 - mx), e1 = expf(v1 - mx);
            float e2 = expf(v2 - mx), e3 = expf(v3 - mx);
            float sum = e0 + e1 + e2 + e3;
            sum += __shfl_xor(sum, 1);
            sum += __shfl_xor(sum, 2);
            sum += __shfl_xor(sum, 4);
            sum += __shfl_xor(sum, 8);
            float inv = 1.0f / sum;
            float pv[4] = {e0 * inv, e1 * inv, e2 * inv, e3 * inv};
            int rowi = fm * 16 + lc * 4 + e;
#pragma unroll
            for (int fn = 0; fn < 4; fn++)
                P32[w][rowi][fn * 16 + lr] = pack_hl(pv[fn]);
        }
    }
    // only intra-wave LDS dependency (each wave owns P32[w])

    f32x4 acc2[4][4];
#pragma unroll
    for (int i = 0; i < 4; i++)
#pragma unroll
        for (int j = 0; j < 4; j++) acc2[i][j] = (f32x4){0.f, 0.f, 0.f, 0.f};

#pragma unroll
    for (int ks = 0; ks < 2; ks++) {
        bf16x8 vh[4], vl[4];
#pragma unroll
        for (int f = 0; f < 4; f++) {
            vh[f] = *(const bf16x8*)(Vth + kboff + f * 1024 + ks * 32);
            vl[f] = *(const bf16x8*)(Vtl + kboff + f * 1024 + ks * 32);
        }
        bf16x8 ph[4], pl[4];
#pragma unroll
        for (int fm = 0; fm < 4; fm++)
            unpack8(&P32[w][fm * 16 + lr][ks * 32 + lc * 8], ph[fm], pl[fm]);
#pragma unroll
        for (int fm = 0; fm < 4; fm++)
#pragma unroll
            for (int fn = 0; fn < 4; fn++) {
                acc2[fm][fn] = __builtin_amdgcn_mfma_f32_16x16x32_bf16(ph[fm], vh[fn], acc2[fm][fn], 0, 0, 0);
                acc2[fm][fn] = __builtin_amdgcn_mfma_f32_16x16x32_bf16(ph[fm], vl[fn], acc2[fm][fn], 0, 0, 0);
                acc2[fm][fn] = __builtin_amdgcn_mfma_f32_16x16x32_bf16(pl[fm], vh[fn], acc2[fm][fn], 0, 0, 0);
            }
    }

    const size_t gbase = ((size_t)(b * S + s0 + lc * 4)) * D_MODEL + h * D_HEAD + lr;
#pragma unroll
    for (int fm = 0; fm < 4; fm++)
#pragma unroll
        for (int e = 0; e < 4; e++) {
            size_t ro = gbase + ((size_t)(fm * 16 + e)) * D_MODEL;
#pragma unroll
            for (int fn = 0; fn < 4; fn++) {
                float v = acc2[fm][fn][e];
                u16 hv = bf16_rtne(v);
                ctx_hi[ro + fn * 16] = hv;
                ctx_lo[ro + fn * 16] = bf16_rtne(v - bf16_to_f32(hv));
            }
        }
}

// ---------------------------------------------------------------------------
extern "C" void kernel_launch(void* const* d_in, const int* in_sizes, int n_in,
                              void* d_out, int out_size, void* d_ws, size_t ws_size,
                              hipStream_t stream)
{
    (void)n_in; (void)out_size; (void)ws_size;
    const float* x       = (const float*)d_in[0];
    const float* Wq      = (const float*)d_in[1];
    const float* bq      = (const float*)d_in[2];
    const float* Wk      = (const float*)d_in[3];
    const float* bk      = (const float*)d_in[4];
    const float* Wv      = (const float*)d_in[5];
    const float* bv      = (const float*)d_in[6];
    const float* Wo      = (const float*)d_in[7];
    const float* bo      = (const float*)d_in[8];
    const float* W_bin   = (const float*)d_in[9];
    const float* proto   = (const float*)d_in[10];
    const float* log_tau = (const float*)d_in[11];
    float* out = (float*)d_out;

    const int M  = in_sizes[0] / D_MODEL;   // B*S = 16384
    const int S  = 4096;
    const int B  = M / S;                   // 4
    const int BH = B * N_HEADS;             // 64
    const int CH = 16;

    const size_t MB = (size_t)1 << 20;
    char* wsb = (char*)d_ws;
    float*          R1   = (float*)wsb;                        // 64 MB: K fp32, later Q hi/lo
    float*          R2   = (float*)(wsb + 64  * MB);           // 64 MB: V fp32
    unsigned short* XShi = (unsigned short*)(wsb + 128 * MB);  // 32 MB: x_hi -> ctx_hi
    unsigned short* XSlo = (unsigned short*)(wsb + 160 * MB);  // 32 MB: x_lo -> ctx_lo
    unsigned short* W4hi = (unsigned short*)(wsb + 192 * MB);  //  8 MB: q,k,v,o concat
    unsigned short* W4lo = (unsigned short*)(wsb + 200 * MB);  //  8 MB
    u16*            Kbh  = (u16*)(wsb + 208 * MB);             // 512 KB each
    u16*            Kbl  = Kbh + (size_t)BH * 4096;
    u16*            Vth  = Kbl + (size_t)BH * 4096;
    u16*            Vtl  = Vth + (size_t)BH * 4096;

    // partials (34.6 MB @ CH=16) scratch lives in d_out (67 MB): fully written
    // by bin_assign_agg, consumed by bin_reduce, then overwritten by final GEMM.
    float* part = (float*)d_out;

    u16* Qhi = (u16*)R1;                       // Q hi/lo overlay R1 (K fp32 dead)
    u16* Qlo = Qhi + (size_t)M * D_MODEL;

    const size_t WOFF = (size_t)D_MODEL * D_MODEL;   // per-weight offset in concat
    const int n8x = (M * D_MODEL) / 8;
    const int n8w = (D_MODEL * D_MODEL) / 8;
    dim3 gg(M / 256, D_MODEL / 256);           // (64, 4)

    split_bf16x2<<<n8x / 256, 256, 0, stream>>>(x, XShi, XSlo, n8x);
    split4_w<<<dim3(n8w / 256, 4), 256, 0, stream>>>(Wq, Wk, Wv, Wo, W4hi, W4lo);

    gemm_bf16x2_nt<false><<<gg, 512, 0, stream>>>(XShi, XSlo, W4hi + WOFF, W4lo + WOFF,
                                                  bk, R1, nullptr, nullptr,
                                                  M, D_MODEL, D_MODEL);
    gemm_bf16x2_nt<false><<<gg, 512, 0, stream>>>(XShi, XSlo, W4hi + 2 * WOFF, W4lo + 2 * WOFF,
                                                  bv, R2, nullptr, nullptr,
                                                  M, D_MODEL, D_MODEL);

    bin_assign_agg<<<dim3(BH, CH), 256, 0, stream>>>(R1, R2, W_bin, proto,
                                                     log_tau, part, B, S);
    bin_reduce<<<BH, 256, 0, stream>>>(part, Kbh, Kbl, Vth, Vtl, CH);

    // Q projection writes bf16 hi/lo directly (R1's fp32 K is consumed above)
    gemm_bf16x2_nt<true><<<gg, 512, 0, stream>>>(XShi, XSlo, W4hi, W4lo,
                                                 bq, nullptr, Qhi, Qlo,
                                                 M, D_MODEL, D_MODEL);

    // ctx hi/lo overwrite XShi/XSlo (x splits dead after Q GEMM)
    bin_attn_mfma<<<dim3(BH, S / 256), 256, 0, stream>>>(Qhi, Qlo, Kbh, Kbl, Vth, Vtl,
                                                         XShi, XSlo, B, S);

    gemm_bf16x2_nt<false><<<gg, 512, 0, stream>>>(XShi, XSlo, W4hi + 3 * WOFF, W4lo + 3 * WOFF,
                                                  bo, out, nullptr, nullptr,
                                                  M, D_MODEL, D_MODEL);
}

// Round 8
// 527.127 us; speedup vs baseline: 1.0252x; 1.0252x over previous
//
#include <hip/hip_runtime.h>
#include <math.h>

typedef float f4 __attribute__((ext_vector_type(4)));
typedef float f32x4 __attribute__((ext_vector_type(4)));
typedef short bf16x8 __attribute__((ext_vector_type(8)));
typedef unsigned int u32x4 __attribute__((ext_vector_type(4)));
typedef unsigned int u32x2 __attribute__((ext_vector_type(2)));
typedef unsigned short u16;
typedef unsigned int u32;

#define D_MODEL 1024
#define N_HEADS 16
#define D_HEAD  64
#define N_BINS  64
#define D_LAT   8

// ---------------------------------------------------------------------------
// bf16 split helpers (RTNE)
// ---------------------------------------------------------------------------
__device__ __forceinline__ unsigned short bf16_rtne(float f) {
    unsigned int u = __builtin_bit_cast(unsigned int, f);
    u += 0x7FFFu + ((u >> 16) & 1u);
    return (unsigned short)(u >> 16);
}
__device__ __forceinline__ float bf16_to_f32(unsigned short h) {
    unsigned int u = ((unsigned int)h) << 16;
    return __builtin_bit_cast(float, u);
}
__device__ __forceinline__ u32 pack_hl(float v) {
    unsigned short h = bf16_rtne(v);
    unsigned short l = bf16_rtne(v - bf16_to_f32(h));
    return (u32)h | ((u32)l << 16);
}
// unpack 8 consecutive packed (hi | lo<<16) u32 -> hi-frag, lo-frag
__device__ __forceinline__ void unpack8(const u32* p, bf16x8& hf, bf16x8& lf) {
    u32x4 r0 = *(const u32x4*)p;
    u32x4 r1 = *(const u32x4*)(p + 4);
    u32x4 hv, lv;
    hv[0] = (r0[0] & 0xffffu) | (r0[1] << 16);  lv[0] = (r0[0] >> 16) | (r0[1] & 0xffff0000u);
    hv[1] = (r0[2] & 0xffffu) | (r0[3] << 16);  lv[1] = (r0[2] >> 16) | (r0[3] & 0xffff0000u);
    hv[2] = (r1[0] & 0xffffu) | (r1[1] << 16);  lv[2] = (r1[0] >> 16) | (r1[1] & 0xffff0000u);
    hv[3] = (r1[2] & 0xffffu) | (r1[3] << 16);  lv[3] = (r1[2] >> 16) | (r1[3] & 0xffff0000u);
    hf = __builtin_bit_cast(bf16x8, hv);
    lf = __builtin_bit_cast(bf16x8, lv);
}

// fp32 -> (hi, lo) bf16 buffers, 8 elems/thread
__global__ __launch_bounds__(256)
void split_bf16x2(const float* __restrict__ in, unsigned short* __restrict__ hi,
                  unsigned short* __restrict__ lo, int n8)
{
    int i = blockIdx.x * 256 + threadIdx.x;
    if (i >= n8) return;
    const f4* inp = (const f4*)in;
    f4 a = inp[2 * i];
    f4 b = inp[2 * i + 1];
    unsigned short hs[8], ls[8];
#pragma unroll
    for (int j = 0; j < 8; j++) {
        float v = (j < 4) ? a[j] : b[j - 4];
        unsigned short h = bf16_rtne(v);
        hs[j] = h;
        ls[j] = bf16_rtne(v - bf16_to_f32(h));
    }
    u32x4 ho, lv;
#pragma unroll
    for (int j = 0; j < 4; j++) {
        ho[j] = (unsigned int)hs[2 * j] | ((unsigned int)hs[2 * j + 1] << 16);
        lv[j] = (unsigned int)ls[2 * j] | ((unsigned int)ls[2 * j + 1] << 16);
    }
    ((u32x4*)hi)[i] = ho;
    ((u32x4*)lo)[i] = lv;
}

// all four weight matrices -> one concat hi/lo buffer (order q,k,v,o)
__global__ __launch_bounds__(256)
void split4_w(const float* __restrict__ w0, const float* __restrict__ w1,
              const float* __restrict__ w2, const float* __restrict__ w3,
              unsigned short* __restrict__ hi, unsigned short* __restrict__ lo)
{
    const int which = blockIdx.y;
    const float* in = (which == 0) ? w0 : (which == 1) ? w1 : (which == 2) ? w2 : w3;
    int i = blockIdx.x * 256 + threadIdx.x;          // item of 8 elems
    const f4* inp = (const f4*)in;
    f4 a = inp[2 * i];
    f4 b = inp[2 * i + 1];
    unsigned short hs[8], ls[8];
#pragma unroll
    for (int j = 0; j < 8; j++) {
        float v = (j < 4) ? a[j] : b[j - 4];
        unsigned short h = bf16_rtne(v);
        hs[j] = h;
        ls[j] = bf16_rtne(v - bf16_to_f32(h));
    }
    u32x4 ho, lv;
#pragma unroll
    for (int j = 0; j < 4; j++) {
        ho[j] = (unsigned int)hs[2 * j] | ((unsigned int)hs[2 * j + 1] << 16);
        lv[j] = (unsigned int)ls[2 * j] | ((unsigned int)ls[2 * j + 1] << 16);
    }
    size_t off = (size_t)which * (D_MODEL * D_MODEL / 8);
    ((u32x4*)hi)[off + i] = ho;
    ((u32x4*)lo)[off + i] = lv;
}

// ---------------------------------------------------------------------------
// Split-bf16 MFMA GEMM (NT): C[M,N] = (Ahi+Alo)[M,K] * (Whi+Wlo)[N,K]^T + bias
// 256x256 tile, BK=32, 512 threads (8 waves as 2Mx4N, each 128x64 out),
// double-buffered 128KB LDS via global_load_lds(16B), conflict-free
// (r>>1)&3 chunk-XOR swizzle (bank-conflict = 0, verified r6).
// Schedule (r8 fix of r7): ALL 8 prefetch loads for tile t+1 are issued at
// the TOP of phase 0, giving them phases 0-2 (~2500+ cyc of MFMA) to land
// before the single vmcnt(0) drain at the tile flip. r7's bug: Blo loads
// issued in the last phase right before vmcnt(0) -> exposed HBM latency.
// 3 phases/tile: P0 {issue 8 glds; read A0-3+B0-1; 24 MFMA}, P1 {read B2-3;
// 24 MFMA}, P2 {read A4-7; 48 MFMA}, flip {vmcnt(0); barrier}.
// ---------------------------------------------------------------------------
__device__ __forceinline__ void glds16(const unsigned short* g, unsigned short* l) {
    __builtin_amdgcn_global_load_lds((const __attribute__((address_space(1))) void*)g,
                                     (__attribute__((address_space(3))) void*)l,
                                     16, 0, 0);
}

#define MFMA3(ACC, AH, AL, BH, BL) do {                                        \
    f32x4 _a = (ACC);                                                          \
    _a = __builtin_amdgcn_mfma_f32_16x16x32_bf16((AH), (BH), _a, 0, 0, 0);     \
    _a = __builtin_amdgcn_mfma_f32_16x16x32_bf16((AH), (BL), _a, 0, 0, 0);     \
    _a = __builtin_amdgcn_mfma_f32_16x16x32_bf16((AL), (BH), _a, 0, 0, 0);     \
    (ACC) = _a;                                                                \
} while (0)

template<bool SPLIT>
__global__ __launch_bounds__(512)
void gemm_bf16x2_nt(const unsigned short* __restrict__ Ahi, const unsigned short* __restrict__ Alo,
                    const unsigned short* __restrict__ Bhi, const unsigned short* __restrict__ Blo,
                    const float* __restrict__ bias, float* __restrict__ C,
                    unsigned short* __restrict__ Chi, unsigned short* __restrict__ Clo,
                    int M, int N, int K)
{
    __shared__ unsigned short lds[2][4][8192];   // [dbuf][Ahi,Alo,Bhi,Blo][256r x 32k]

    const int tid  = threadIdx.x;
    const int lane = tid & 63;
    const int w    = tid >> 6;
    const int wm   = w >> 2;         // 0..1
    const int wn   = w & 3;          // 0..3
    const int bm   = blockIdx.x * 256;
    const int bn   = blockIdx.y * 256;

    // staging: seg s covers rows [s*16,s*16+16); wave w handles s = i*8+w.
    // row-within-seg = lane>>2 => row bits 1..2 = (lane>>3)&3.
    const int schunk = (lane & 3) ^ ((lane >> 3) & 3);
    size_t gA[2], gB[2];
    int    seg[2];
#pragma unroll
    for (int i = 0; i < 2; i++) {
        int s = i * 8 + w;
        int r = s * 16 + (lane >> 2);
        gA[i]  = (size_t)(bm + r) * K + schunk * 8;
        gB[i]  = (size_t)(bn + r) * K + schunk * 8;
        seg[i] = s * 512;            // ushort offset of 1KB segment
    }

    // fragment read: row = base16 + (lane&15); slot = (lane>>4) ^ ((row>>1)&3)
    const int koff  = ((lane >> 4) ^ ((lane >> 1) & 3)) * 8;
    const int abase = (wm * 128 + (lane & 15)) * 32 + koff;
    const int bbase = (wn * 64  + (lane & 15)) * 32 + koff;

    f32x4 acc[8][4];
#pragma unroll
    for (int i = 0; i < 8; i++)
#pragma unroll
        for (int j = 0; j < 4; j++) acc[i][j] = (f32x4){0.f, 0.f, 0.f, 0.f};

    // prologue: stage tile 0, drain, sync
#pragma unroll
    for (int i = 0; i < 2; i++) {
        glds16(Ahi + gA[i], &lds[0][0][seg[i]]);
        glds16(Alo + gA[i], &lds[0][1][seg[i]]);
        glds16(Bhi + gB[i], &lds[0][2][seg[i]]);
        glds16(Blo + gB[i], &lds[0][3][seg[i]]);
    }
    asm volatile("s_waitcnt vmcnt(0)" ::: "memory");
    __builtin_amdgcn_s_barrier();

    const int nt = K / 32;
    for (int t = 0; t < nt; t++) {
        const int cur = t & 1;
        const int nxt = cur ^ 1;
        const bool pre = (t + 1 < nt);
        const int kt = (t + 1) * 32;

        bf16x8 a0h[4], a0l[4], a1h[4], a1l[4];
        bf16x8 b0h[2], b0l[2], b1h[2], b1l[2];

        // ---------- phase 0: issue ALL prefetch, read A0..3 + B0..1, MFMA q00 ----------
        if (pre) {
#pragma unroll
            for (int i = 0; i < 2; i++) {
                glds16(Ahi + gA[i] + kt, &lds[nxt][0][seg[i]]);
                glds16(Alo + gA[i] + kt, &lds[nxt][1][seg[i]]);
                glds16(Bhi + gB[i] + kt, &lds[nxt][2][seg[i]]);
                glds16(Blo + gB[i] + kt, &lds[nxt][3][seg[i]]);
            }
        }
#pragma unroll
        for (int i = 0; i < 4; i++) {
            a0h[i] = *(const bf16x8*)&lds[cur][0][abase + i * 512];
            a0l[i] = *(const bf16x8*)&lds[cur][1][abase + i * 512];
        }
#pragma unroll
        for (int j = 0; j < 2; j++) {
            b0h[j] = *(const bf16x8*)&lds[cur][2][bbase + j * 512];
            b0l[j] = *(const bf16x8*)&lds[cur][3][bbase + j * 512];
        }
        __builtin_amdgcn_s_setprio(1);
#pragma unroll
        for (int i = 0; i < 4; i++)
#pragma unroll
            for (int j = 0; j < 2; j++)
                MFMA3(acc[i][j], a0h[i], a0l[i], b0h[j], b0l[j]);
        __builtin_amdgcn_s_setprio(0);
        __builtin_amdgcn_s_barrier();

        // ---------- phase 1: read B2..3, MFMA q01 ----------
#pragma unroll
        for (int j = 0; j < 2; j++) {
            b1h[j] = *(const bf16x8*)&lds[cur][2][bbase + (2 + j) * 512];
            b1l[j] = *(const bf16x8*)&lds[cur][3][bbase + (2 + j) * 512];
        }
        __builtin_amdgcn_s_setprio(1);
#pragma unroll
        for (int i = 0; i < 4; i++)
#pragma unroll
            for (int j = 0; j < 2; j++)
                MFMA3(acc[i][2 + j], a0h[i], a0l[i], b1h[j], b1l[j]);
        __builtin_amdgcn_s_setprio(0);
        __builtin_amdgcn_s_barrier();

        // ---------- phase 2: read A4..7, MFMA q10 + q11 ----------
#pragma unroll
        for (int i = 0; i < 4; i++) {
            a1h[i] = *(const bf16x8*)&lds[cur][0][abase + (4 + i) * 512];
            a1l[i] = *(const bf16x8*)&lds[cur][1][abase + (4 + i) * 512];
        }
        __builtin_amdgcn_s_setprio(1);
#pragma unroll
        for (int i = 0; i < 4; i++)
#pragma unroll
            for (int j = 0; j < 2; j++) {
                MFMA3(acc[4 + i][j],     a1h[i], a1l[i], b0h[j], b0l[j]);
                MFMA3(acc[4 + i][2 + j], a1h[i], a1l[i], b1h[j], b1l[j]);
            }
        __builtin_amdgcn_s_setprio(0);
        // flip seam: prefetch loads (issued in phase 0, ~2 phases ago) drained
        asm volatile("s_waitcnt vmcnt(0)" ::: "memory");
        __builtin_amdgcn_s_barrier();
    }

    // epilogue: C/D layout col = lane&15, row = (lane>>4)*4 + e
    const int rb = bm + wm * 128;
    const int cb = bn + wn * 64;
    float bv[4];
#pragma unroll
    for (int fn = 0; fn < 4; fn++) bv[fn] = bias[cb + fn * 16 + (lane & 15)];
#pragma unroll
    for (int fm = 0; fm < 8; fm++)
#pragma unroll
        for (int e = 0; e < 4; e++) {
            size_t row = (size_t)(rb + fm * 16 + (lane >> 4) * 4 + e);
            if constexpr (SPLIT) {
#pragma unroll
                for (int fn = 0; fn < 4; fn++) {
                    float v = acc[fm][fn][e] + bv[fn];
                    unsigned short h = bf16_rtne(v);
                    Chi[row * N + cb + fn * 16 + (lane & 15)] = h;
                    Clo[row * N + cb + fn * 16 + (lane & 15)] = bf16_rtne(v - bf16_to_f32(h));
                }
            } else {
                float* cp = &C[row * N];
#pragma unroll
                for (int fn = 0; fn < 4; fn++)
                    cp[cb + fn * 16 + (lane & 15)] = acc[fm][fn][e] + bv[fn];
            }
        }
}

// ---------------------------------------------------------------------------
// Bin assignment + soft aggregation (MFMA aggregation; unchanged from r6).
// ---------------------------------------------------------------------------
__global__ __launch_bounds__(256)
void bin_assign_agg(const float* __restrict__ Kbuf, const float* __restrict__ Vbuf,
                    const float* __restrict__ W_bin, const float* __restrict__ proto,
                    const float* __restrict__ log_tau,
                    float* __restrict__ partials, int B, int S)
{
    __shared__ __attribute__((aligned(16))) float Wb[8][64];
    __shared__ __attribute__((aligned(16))) float Prt[8][64];
    __shared__ __attribute__((aligned(16))) float zsm[64][8];
    __shared__ __attribute__((aligned(16))) float Kt[64][68];
    __shared__ __attribute__((aligned(16))) u32 KT32[64][68];   // [d][s] packed hi|lo
    __shared__ __attribute__((aligned(16))) u32 VT32[64][68];
    __shared__ __attribute__((aligned(16))) u32 P32T[64][68];   // [n][s] packed hi|lo

    const int bh = blockIdx.x;
    const int h  = bh & (N_HEADS - 1);
    const int b  = bh >> 4;
    const int chunk = blockIdx.y;
    const int CH = gridDim.y;
    const int tid = threadIdx.x;
    const int lane = tid & 63;
    const int w = tid >> 6;

    if (tid < 128) {
        ((f4*)&Wb[0][0])[tid] = ((const f4*)W_bin)[tid];
    } else {
        int t = tid - 128;
        f4 p = ((const f4*)(proto + (size_t)h * N_BINS * D_LAT))[t];
        int n = t >> 1, l4 = (t & 1) * 4;
        Prt[l4 + 0][n] = p[0];
        Prt[l4 + 1][n] = p[1];
        Prt[l4 + 2][n] = p[2];
        Prt[l4 + 3][n] = p[3];
    }
    const float tau   = fmaxf(expf(log_tau[h]), 1e-3f);
    const float scale = 1.0f / (tau + 1e-8f);

    const int row = tid >> 2, sub = tid & 3;   // softmax: 4 lanes per key row
    const int lr = lane & 15, lc = lane >> 4;  // MFMA fragment indices
    const int mat = w >> 1;                    // 0 = K, 1 = V
    const int fn0 = (w & 1) * 2;               // d fragment pair

    f32x4 acc[4][2];
    f4 cntv[4];
#pragma unroll
    for (int i = 0; i < 4; i++) {
        cntv[i] = (f4){0.f, 0.f, 0.f, 0.f};
        acc[i][0] = (f32x4){0.f, 0.f, 0.f, 0.f};
        acc[i][1] = (f32x4){0.f, 0.f, 0.f, 0.f};
    }

    const int SC = S / CH;
    const int s_base = chunk * SC;

    for (int s0 = 0; s0 < SC; s0 += 64) {
        __syncthreads();   // previous chunk's MFMA reads done before restage
#pragma unroll
        for (int q = 0; q < 2; q++) {
            int item = tid + 256 * q;       // 0..511
            int rp = item >> 4;             // 0..31
            int dc = item & 15;
            int r0 = rp * 2;
            size_t gi = ((size_t)(b * S + s_base + s0 + r0)) * D_MODEL + h * D_HEAD + dc * 4;
            f4 k0 = *(const f4*)&Kbuf[gi];
            f4 k1 = *(const f4*)&Kbuf[gi + D_MODEL];
            f4 v0 = *(const f4*)&Vbuf[gi];
            f4 v1 = *(const f4*)&Vbuf[gi + D_MODEL];
            *(f4*)&Kt[r0][dc * 4]     = k0;
            *(f4*)&Kt[r0 + 1][dc * 4] = k1;
#pragma unroll
            for (int j = 0; j < 4; j++) {
                int d = dc * 4 + j;
                *(u32x2*)&KT32[d][r0] = (u32x2){pack_hl(k0[j]), pack_hl(k1[j])};
                *(u32x2*)&VT32[d][r0] = (u32x2){pack_hl(v0[j]), pack_hl(v1[j])};
            }
        }
        __syncthreads();

        {
            const int l0 = sub * 2;
            f4 z0 = {0.f, 0.f, 0.f, 0.f}, z1 = {0.f, 0.f, 0.f, 0.f};
#pragma unroll
            for (int d4 = 0; d4 < 16; d4++) {
                f4 kv = *(const f4*)&Kt[row][d4 * 4];
                f4 w0 = *(const f4*)&Wb[l0][d4 * 4];
                f4 w1 = *(const f4*)&Wb[l0 + 1][d4 * 4];
                z0 += kv * w0;
                z1 += kv * w1;
            }
            zsm[row][l0]     = z0[0] + z0[1] + z0[2] + z0[3];
            zsm[row][l0 + 1] = z1[0] + z1[1] + z1[2] + z1[3];
        }
        __syncthreads();

        {
            float zr[8];
#pragma unroll
            for (int l = 0; l < 8; l++) zr[l] = zsm[row][l];
            f4 lg[4];
#pragma unroll
            for (int q = 0; q < 4; q++) lg[q] = (f4){0.f, 0.f, 0.f, 0.f};
#pragma unroll
            for (int l = 0; l < 8; l++) {
                float zv = zr[l];
#pragma unroll
                for (int q = 0; q < 4; q++) {
                    f4 pr = *(const f4*)&Prt[l][sub * 16 + q * 4];
                    lg[q] += zv * pr;
                }
            }
            float mx = -1e30f;
#pragma unroll
            for (int q = 0; q < 4; q++) {
                lg[q] *= scale;
                mx = fmaxf(mx, fmaxf(fmaxf(lg[q][0], lg[q][1]), fmaxf(lg[q][2], lg[q][3])));
            }
            mx = fmaxf(mx, __shfl_xor(mx, 1));
            mx = fmaxf(mx, __shfl_xor(mx, 2));
            float sum = 0.f;
            f4 pv[4];
#pragma unroll
            for (int q = 0; q < 4; q++) {
#pragma unroll
                for (int e = 0; e < 4; e++) {
                    float ev = expf(lg[q][e] - mx);
                    pv[q][e] = ev;
                    sum += ev;
                }
            }
            sum += __shfl_xor(sum, 1);
            sum += __shfl_xor(sum, 2);
            float inv = 1.0f / sum;
#pragma unroll
            for (int q = 0; q < 4; q++) {
                pv[q] *= inv;
                cntv[q] += pv[q];
#pragma unroll
                for (int e = 0; e < 4; e++)
                    P32T[sub * 16 + q * 4 + e][row] = pack_hl(pv[q][e]);
            }
        }
        __syncthreads();

#pragma unroll
        for (int ks = 0; ks < 2; ks++) {
            bf16x8 pah[4], pal[4];
#pragma unroll
            for (int fm = 0; fm < 4; fm++)
                unpack8(&P32T[fm * 16 + lr][ks * 32 + lc * 8], pah[fm], pal[fm]);
#pragma unroll
            for (int fnL = 0; fnL < 2; fnL++) {
                int dr = (fn0 + fnL) * 16 + lr;
                bf16x8 bhf, blf;
                const u32* bp = mat ? &VT32[dr][ks * 32 + lc * 8]
                                    : &KT32[dr][ks * 32 + lc * 8];
                unpack8(bp, bhf, blf);
#pragma unroll
                for (int fm = 0; fm < 4; fm++) {
                    f32x4 a = acc[fm][fnL];
                    a = __builtin_amdgcn_mfma_f32_16x16x32_bf16(pah[fm], bhf, a, 0, 0, 0);
                    a = __builtin_amdgcn_mfma_f32_16x16x32_bf16(pah[fm], blf, a, 0, 0, 0);
                    a = __builtin_amdgcn_mfma_f32_16x16x32_bf16(pal[fm], bhf, a, 0, 0, 0);
                    acc[fm][fnL] = a;
                }
            }
        }
    }

#pragma unroll
    for (int q = 0; q < 4; q++)
#pragma unroll
        for (int e = 0; e < 4; e++) {
            float c = cntv[q][e];
            c += __shfl_xor(c, 4);
            c += __shfl_xor(c, 8);
            c += __shfl_xor(c, 16);
            c += __shfl_xor(c, 32);
            cntv[q][e] = c;
        }

    float* base = partials + ((size_t)bh * CH + chunk) * 8448;
#pragma unroll
    for (int fm = 0; fm < 4; fm++)
#pragma unroll
        for (int fnL = 0; fnL < 2; fnL++)
#pragma unroll
            for (int e = 0; e < 4; e++) {
                int n = fm * 16 + lc * 4 + e;
                int d = (fn0 + fnL) * 16 + lr;
                base[mat * 4096 + (size_t)n * 64 + d] = acc[fm][fnL][e];
            }
    if ((lane >> 2) == 0) {   // lanes 0..3, sub = lane
#pragma unroll
        for (int q = 0; q < 4; q++)
#pragma unroll
            for (int e = 0; e < 4; e++)
                base[8192 + w * 64 + sub * 16 + q * 4 + e] = cntv[q][e];
    }
}

// ---------------------------------------------------------------------------
// Reduce partials -> bf16 hi/lo K_binned [bh][n][d] and V_binned^T [bh][d][n].
// FAITHFUL to reference broadcast bug: feature d divided by counts[d].
// ---------------------------------------------------------------------------
__global__ __launch_bounds__(256)
void bin_reduce(const float* __restrict__ partials,
                u16* __restrict__ Kbh, u16* __restrict__ Kbl,
                u16* __restrict__ Vth, u16* __restrict__ Vtl, int CH)
{
    const int bh = blockIdx.x;
    const int tid = threadIdx.x;
    __shared__ float inv_cnt[64];
    const float* base = partials + (size_t)bh * CH * 8448;
    if (tid < 64) {
        float c = 0.f;
        for (int ch = 0; ch < CH; ch++)
#pragma unroll
            for (int ww = 0; ww < 4; ww++)
                c += base[(size_t)ch * 8448 + 8192 + ww * 64 + tid];
        inv_cnt[tid] = 1.0f / (c + 1e-6f);
    }
    __syncthreads();
    for (int idx = tid; idx < 4096; idx += 256) {
        float k = 0.f, v = 0.f;
        for (int ch = 0; ch < CH; ch++) {
            const float* p = base + (size_t)ch * 8448;
            k += p[idx];
            v += p[4096 + idx];
        }
        float ic = inv_cnt[idx & 63];   // divide by count of FEATURE index d
        k *= ic;
        v *= ic;
        int n = idx >> 6, d = idx & 63;
        u16 kh = bf16_rtne(k);
        Kbh[(size_t)bh * 4096 + idx] = kh;
        Kbl[(size_t)bh * 4096 + idx] = bf16_rtne(k - bf16_to_f32(kh));
        u16 vh = bf16_rtne(v);
        size_t ti = (size_t)bh * 4096 + (size_t)d * 64 + n;   // transposed
        Vth[ti] = vh;
        Vtl[ti] = bf16_rtne(v - bf16_to_f32(vh));
    }
}

// ---------------------------------------------------------------------------
// Bin attention via bf16x2 MFMA (unchanged, passing).
// ---------------------------------------------------------------------------
__global__ __launch_bounds__(256)
void bin_attn_mfma(const u16* __restrict__ Qhi, const u16* __restrict__ Qlo,
                   const u16* __restrict__ Kbh, const u16* __restrict__ Kbl,
                   const u16* __restrict__ Vth, const u16* __restrict__ Vtl,
                   u16* __restrict__ ctx_hi, u16* __restrict__ ctx_lo,
                   int B, int S)
{
    __shared__ unsigned int P32[4][64][68];

    const int bh = blockIdx.x;
    const int h  = bh & (N_HEADS - 1);
    const int b  = bh >> 4;
    const int tid = threadIdx.x;
    const int l  = tid & 63;
    const int w  = tid >> 6;
    const int s0 = blockIdx.y * 256 + w * 64;

    const int lr = l & 15;
    const int lc = l >> 4;

    const size_t qoff  = ((size_t)(b * S + s0 + lr)) * D_MODEL + h * D_HEAD + lc * 8;
    const size_t kboff = (size_t)bh * 4096 + (size_t)lr * 64 + lc * 8;

    f32x4 acc[4][4];
#pragma unroll
    for (int i = 0; i < 4; i++)
#pragma unroll
        for (int j = 0; j < 4; j++) acc[i][j] = (f32x4){0.f, 0.f, 0.f, 0.f};

#pragma unroll
    for (int ks = 0; ks < 2; ks++) {
        bf16x8 qh[4], ql[4], kh[4], kl[4];
#pragma unroll
        for (int f = 0; f < 4; f++) {
            qh[f] = *(const bf16x8*)(Qhi + qoff + f * 16 * D_MODEL + ks * 32);
            ql[f] = *(const bf16x8*)(Qlo + qoff + f * 16 * D_MODEL + ks * 32);
            kh[f] = *(const bf16x8*)(Kbh + kboff + f * 1024 + ks * 32);
            kl[f] = *(const bf16x8*)(Kbl + kboff + f * 1024 + ks * 32);
        }
#pragma unroll
        for (int fm = 0; fm < 4; fm++)
#pragma unroll
            for (int fn = 0; fn < 4; fn++) {
                acc[fm][fn] = __builtin_amdgcn_mfma_f32_16x16x32_bf16(qh[fm], kh[fn], acc[fm][fn], 0, 0, 0);
                acc[fm][fn] = __builtin_amdgcn_mfma_f32_16x16x32_bf16(qh[fm], kl[fn], acc[fm][fn], 0, 0, 0);
                acc[fm][fn] = __builtin_amdgcn_mfma_f32_16x16x32_bf16(ql[fm], kh[fn], acc[fm][fn], 0, 0, 0);
            }
    }

#pragma unroll
    for (int fm = 0; fm < 4; fm++) {
#pragma unroll
        for (int e = 0; e < 4; e++) {
            float v0 = acc[fm][0][e] * 0.125f;
            float v1 = acc[fm][1][e] * 0.125f;
            float v2 = acc[fm][2][e] * 0.125f;
            float v3 = acc[fm][3][e] * 0.125f;
            float mx = fmaxf(fmaxf(v0, v1), fmaxf(v2, v3));
            mx = fmaxf(mx, __shfl_xor(mx, 1));
            mx = fmaxf(mx, __shfl_xor(mx, 2));
            mx = fmaxf(mx, __shfl_xor(mx, 4));
            mx = fmaxf(mx, __shfl_xor(mx, 8));
            float e0 = expf(v0 - mx), e1 = expf(v1 - mx);
            float e2 = expf(v2 - mx), e3 = expf(v3 - mx);
            float sum = e0 + e1 + e2 + e3;
            sum += __shfl_xor(sum, 1);
            sum += __shfl_xor(sum, 2);
            sum += __shfl_xor(sum, 4);
            sum += __shfl_xor(sum, 8);
            float inv = 1.0f / sum;
            float pv[4] = {e0 * inv, e1 * inv, e2 * inv, e3 * inv};
            int rowi = fm * 16 + lc * 4 + e;
#pragma unroll
            for (int fn = 0; fn < 4; fn++)
                P32[w][rowi][fn * 16 + lr] = pack_hl(pv[fn]);
        }
    }
    // only intra-wave LDS dependency (each wave owns P32[w])

    f32x4 acc2[4][4];
#pragma unroll
    for (int i = 0; i < 4; i++)
#pragma unroll
        for (int j = 0; j < 4; j++) acc2[i][j] = (f32x4){0.f, 0.f, 0.f, 0.f};

#pragma unroll
    for (int ks = 0; ks < 2; ks++) {
        bf16x8 vh[4], vl[4];
#pragma unroll
        for (int f = 0; f < 4; f++) {
            vh[f] = *(const bf16x8*)(Vth + kboff + f * 1024 + ks * 32);
            vl[f] = *(const bf16x8*)(Vtl + kboff + f * 1024 + ks * 32);
        }
        bf16x8 ph[4], pl[4];
#pragma unroll
        for (int fm = 0; fm < 4; fm++)
            unpack8(&P32[w][fm * 16 + lr][ks * 32 + lc * 8], ph[fm], pl[fm]);
#pragma unroll
        for (int fm = 0; fm < 4; fm++)
#pragma unroll
            for (int fn = 0; fn < 4; fn++) {
                acc2[fm][fn] = __builtin_amdgcn_mfma_f32_16x16x32_bf16(ph[fm], vh[fn], acc2[fm][fn], 0, 0, 0);
                acc2[fm][fn] = __builtin_amdgcn_mfma_f32_16x16x32_bf16(ph[fm], vl[fn], acc2[fm][fn], 0, 0, 0);
                acc2[fm][fn] = __builtin_amdgcn_mfma_f32_16x16x32_bf16(pl[fm], vh[fn], acc2[fm][fn], 0, 0, 0);
            }
    }

    const size_t gbase = ((size_t)(b * S + s0 + lc * 4)) * D_MODEL + h * D_HEAD + lr;
#pragma unroll
    for (int fm = 0; fm < 4; fm++)
#pragma unroll
        for (int e = 0; e < 4; e++) {
            size_t ro = gbase + ((size_t)(fm * 16 + e)) * D_MODEL;
#pragma unroll
            for (int fn = 0; fn < 4; fn++) {
                float v = acc2[fm][fn][e];
                u16 hv = bf16_rtne(v);
                ctx_hi[ro + fn * 16] = hv;
                ctx_lo[ro + fn * 16] = bf16_rtne(v - bf16_to_f32(hv));
            }
        }
}

// ---------------------------------------------------------------------------
extern "C" void kernel_launch(void* const* d_in, const int* in_sizes, int n_in,
                              void* d_out, int out_size, void* d_ws, size_t ws_size,
                              hipStream_t stream)
{
    (void)n_in; (void)out_size; (void)ws_size;
    const float* x       = (const float*)d_in[0];
    const float* Wq      = (const float*)d_in[1];
    const float* bq      = (const float*)d_in[2];
    const float* Wk      = (const float*)d_in[3];
    const float* bk      = (const float*)d_in[4];
    const float* Wv      = (const float*)d_in[5];
    const float* bv      = (const float*)d_in[6];
    const float* Wo      = (const float*)d_in[7];
    const float* bo      = (const float*)d_in[8];
    const float* W_bin   = (const float*)d_in[9];
    const float* proto   = (const float*)d_in[10];
    const float* log_tau = (const float*)d_in[11];
    float* out = (float*)d_out;

    const int M  = in_sizes[0] / D_MODEL;   // B*S = 16384
    const int S  = 4096;
    const int B  = M / S;                   // 4
    const int BH = B * N_HEADS;             // 64
    const int CH = 8;

    const size_t MB = (size_t)1 << 20;
    char* wsb = (char*)d_ws;
    float*          R1   = (float*)wsb;                        // 64 MB: K fp32, later Q hi/lo
    float*          R2   = (float*)(wsb + 64  * MB);           // 64 MB: V fp32
    unsigned short* XShi = (unsigned short*)(wsb + 128 * MB);  // 32 MB: x_hi -> ctx_hi
    unsigned short* XSlo = (unsigned short*)(wsb + 160 * MB);  // 32 MB: x_lo -> ctx_lo
    unsigned short* W4hi = (unsigned short*)(wsb + 192 * MB);  //  8 MB: q,k,v,o concat
    unsigned short* W4lo = (unsigned short*)(wsb + 200 * MB);  //  8 MB
    u16*            Kbh  = (u16*)(wsb + 208 * MB);             // 512 KB each
    u16*            Kbl  = Kbh + (size_t)BH * 4096;
    u16*            Vth  = Kbl + (size_t)BH * 4096;
    u16*            Vtl  = Vth + (size_t)BH * 4096;

    // partials (17.3 MB @ CH=8) scratch lives in d_out (67 MB): fully written
    // by bin_assign_agg, consumed by bin_reduce, then overwritten by final GEMM.
    float* part = (float*)d_out;

    u16* Qhi = (u16*)R1;                       // Q hi/lo overlay R1 (K fp32 dead)
    u16* Qlo = Qhi + (size_t)M * D_MODEL;

    const size_t WOFF = (size_t)D_MODEL * D_MODEL;   // per-weight offset in concat
    const int n8x = (M * D_MODEL) / 8;
    const int n8w = (D_MODEL * D_MODEL) / 8;
    dim3 gg(M / 256, D_MODEL / 256);           // (64, 4)

    split_bf16x2<<<n8x / 256, 256, 0, stream>>>(x, XShi, XSlo, n8x);
    split4_w<<<dim3(n8w / 256, 4), 256, 0, stream>>>(Wq, Wk, Wv, Wo, W4hi, W4lo);

    gemm_bf16x2_nt<false><<<gg, 512, 0, stream>>>(XShi, XSlo, W4hi + WOFF, W4lo + WOFF,
                                                  bk, R1, nullptr, nullptr,
                                                  M, D_MODEL, D_MODEL);
    gemm_bf16x2_nt<false><<<gg, 512, 0, stream>>>(XShi, XSlo, W4hi + 2 * WOFF, W4lo + 2 * WOFF,
                                                  bv, R2, nullptr, nullptr,
                                                  M, D_MODEL, D_MODEL);

    bin_assign_agg<<<dim3(BH, CH), 256, 0, stream>>>(R1, R2, W_bin, proto,
                                                     log_tau, part, B, S);
    bin_reduce<<<BH, 256, 0, stream>>>(part, Kbh, Kbl, Vth, Vtl, CH);

    // Q projection writes bf16 hi/lo directly (R1's fp32 K is consumed above)
    gemm_bf16x2_nt<true><<<gg, 512, 0, stream>>>(XShi, XSlo, W4hi, W4lo,
                                                 bq, nullptr, Qhi, Qlo,
                                                 M, D_MODEL, D_MODEL);

    // ctx hi/lo overwrite XShi/XSlo (x splits dead after Q GEMM)
    bin_attn_mfma<<<dim3(BH, S / 256), 256, 0, stream>>>(Qhi, Qlo, Kbh, Kbl, Vth, Vtl,
                                                         XShi, XSlo, B, S);

    gemm_bf16x2_nt<false><<<gg, 512, 0, stream>>>(XShi, XSlo, W4hi + 3 * WOFF, W4lo + 3 * WOFF,
                                                  bo, out, nullptr, nullptr,
                                                  M, D_MODEL, D_MODEL);
}

// Round 9
// 495.919 us; speedup vs baseline: 1.0898x; 1.0629x over previous
//
#include <hip/hip_runtime.h>
#include <math.h>

typedef float f4 __attribute__((ext_vector_type(4)));
typedef float f32x4 __attribute__((ext_vector_type(4)));
typedef short bf16x8 __attribute__((ext_vector_type(8)));
typedef unsigned int u32x4 __attribute__((ext_vector_type(4)));
typedef unsigned int u32x2 __attribute__((ext_vector_type(2)));
typedef unsigned short u16;
typedef unsigned int u32;

#define D_MODEL 1024
#define N_HEADS 16
#define D_HEAD  64
#define N_BINS  64
#define D_LAT   8

// ---------------------------------------------------------------------------
// bf16 split helpers (RTNE)
// ---------------------------------------------------------------------------
__device__ __forceinline__ unsigned short bf16_rtne(float f) {
    unsigned int u = __builtin_bit_cast(unsigned int, f);
    u += 0x7FFFu + ((u >> 16) & 1u);
    return (unsigned short)(u >> 16);
}
__device__ __forceinline__ float bf16_to_f32(unsigned short h) {
    unsigned int u = ((unsigned int)h) << 16;
    return __builtin_bit_cast(float, u);
}
__device__ __forceinline__ u32 pack_hl(float v) {
    unsigned short h = bf16_rtne(v);
    unsigned short l = bf16_rtne(v - bf16_to_f32(h));
    return (u32)h | ((u32)l << 16);
}
// unpack 8 consecutive packed (hi | lo<<16) u32 -> hi-frag, lo-frag
__device__ __forceinline__ void unpack8(const u32* p, bf16x8& hf, bf16x8& lf) {
    u32x4 r0 = *(const u32x4*)p;
    u32x4 r1 = *(const u32x4*)(p + 4);
    u32x4 hv, lv;
    hv[0] = (r0[0] & 0xffffu) | (r0[1] << 16);  lv[0] = (r0[0] >> 16) | (r0[1] & 0xffff0000u);
    hv[1] = (r0[2] & 0xffffu) | (r0[3] << 16);  lv[1] = (r0[2] >> 16) | (r0[3] & 0xffff0000u);
    hv[2] = (r1[0] & 0xffffu) | (r1[1] << 16);  lv[2] = (r1[0] >> 16) | (r1[1] & 0xffff0000u);
    hv[3] = (r1[2] & 0xffffu) | (r1[3] << 16);  lv[3] = (r1[2] >> 16) | (r1[3] & 0xffff0000u);
    hf = __builtin_bit_cast(bf16x8, hv);
    lf = __builtin_bit_cast(bf16x8, lv);
}

// fp32 -> (hi, lo) bf16 buffers, 8 elems/thread
__global__ __launch_bounds__(256)
void split_bf16x2(const float* __restrict__ in, unsigned short* __restrict__ hi,
                  unsigned short* __restrict__ lo, int n8)
{
    int i = blockIdx.x * 256 + threadIdx.x;
    if (i >= n8) return;
    const f4* inp = (const f4*)in;
    f4 a = inp[2 * i];
    f4 b = inp[2 * i + 1];
    unsigned short hs[8], ls[8];
#pragma unroll
    for (int j = 0; j < 8; j++) {
        float v = (j < 4) ? a[j] : b[j - 4];
        unsigned short h = bf16_rtne(v);
        hs[j] = h;
        ls[j] = bf16_rtne(v - bf16_to_f32(h));
    }
    u32x4 ho, lv;
#pragma unroll
    for (int j = 0; j < 4; j++) {
        ho[j] = (unsigned int)hs[2 * j] | ((unsigned int)hs[2 * j + 1] << 16);
        lv[j] = (unsigned int)ls[2 * j] | ((unsigned int)ls[2 * j + 1] << 16);
    }
    ((u32x4*)hi)[i] = ho;
    ((u32x4*)lo)[i] = lv;
}

// all four weight matrices -> one concat hi/lo buffer (order q,k,v,o)
__global__ __launch_bounds__(256)
void split4_w(const float* __restrict__ w0, const float* __restrict__ w1,
              const float* __restrict__ w2, const float* __restrict__ w3,
              unsigned short* __restrict__ hi, unsigned short* __restrict__ lo)
{
    const int which = blockIdx.y;
    const float* in = (which == 0) ? w0 : (which == 1) ? w1 : (which == 2) ? w2 : w3;
    int i = blockIdx.x * 256 + threadIdx.x;          // item of 8 elems
    const f4* inp = (const f4*)in;
    f4 a = inp[2 * i];
    f4 b = inp[2 * i + 1];
    unsigned short hs[8], ls[8];
#pragma unroll
    for (int j = 0; j < 8; j++) {
        float v = (j < 4) ? a[j] : b[j - 4];
        unsigned short h = bf16_rtne(v);
        hs[j] = h;
        ls[j] = bf16_rtne(v - bf16_to_f32(h));
    }
    u32x4 ho, lv;
#pragma unroll
    for (int j = 0; j < 4; j++) {
        ho[j] = (unsigned int)hs[2 * j] | ((unsigned int)hs[2 * j + 1] << 16);
        lv[j] = (unsigned int)ls[2 * j] | ((unsigned int)ls[2 * j + 1] << 16);
    }
    size_t off = (size_t)which * (D_MODEL * D_MODEL / 8);
    ((u32x4*)hi)[off + i] = ho;
    ((u32x4*)lo)[off + i] = lv;
}

// ---------------------------------------------------------------------------
// Split-bf16 MFMA GEMM (NT): C[M,N] = (Ahi+Alo)[M,K] * (Whi+Wlo)[N,K]^T + bias
// 256x256 tile, BK=32, 512 threads (8 waves as 2Mx4N, each 128x64 out),
// double-buffered 128KB LDS via global_load_lds(16B), conflict-free
// (r>>1)&3 chunk-XOR swizzle. Schedule = r6's proven 2-phase loop (r7/r8
// phase-split variants both regressed: barriers cost more than the overlap).
// bias2/nsplit: for the fused KV call (N=2048), columns >= nsplit take bias2
// (per-block uniform since tiles never straddle the 1024 boundary).
// ---------------------------------------------------------------------------
__device__ __forceinline__ void glds16(const unsigned short* g, unsigned short* l) {
    __builtin_amdgcn_global_load_lds((const __attribute__((address_space(1))) void*)g,
                                     (__attribute__((address_space(3))) void*)l,
                                     16, 0, 0);
}

template<bool SPLIT>
__global__ __launch_bounds__(512)
void gemm_bf16x2_nt(const unsigned short* __restrict__ Ahi, const unsigned short* __restrict__ Alo,
                    const unsigned short* __restrict__ Bhi, const unsigned short* __restrict__ Blo,
                    const float* __restrict__ bias, const float* __restrict__ bias2, int nsplit,
                    float* __restrict__ C,
                    unsigned short* __restrict__ Chi, unsigned short* __restrict__ Clo,
                    int M, int N, int K)
{
    __shared__ unsigned short lds[2][4][8192];   // [dbuf][Ahi,Alo,Bhi,Blo][256r x 32k]

    const int tid  = threadIdx.x;
    const int lane = tid & 63;
    const int w    = tid >> 6;
    const int wm   = w >> 2;         // 0..1
    const int wn   = w & 3;          // 0..3
    const int bm   = blockIdx.x * 256;
    const int bn   = blockIdx.y * 256;

    // staging: seg s covers rows [s*16,s*16+16); wave w handles s = i*8+w.
    // row-within-seg = lane>>2 => row bits 1..2 = (lane>>3)&3.
    const int schunk = (lane & 3) ^ ((lane >> 3) & 3);
    size_t gA[2], gB[2];
    int    seg[2];
#pragma unroll
    for (int i = 0; i < 2; i++) {
        int s = i * 8 + w;
        int r = s * 16 + (lane >> 2);
        gA[i]  = (size_t)(bm + r) * K + schunk * 8;
        gB[i]  = (size_t)(bn + r) * K + schunk * 8;
        seg[i] = s * 512;            // ushort offset of 1KB segment
    }

    // fragment read: row = base16 + (lane&15); slot = (lane>>4) ^ ((row>>1)&3)
    const int koff  = ((lane >> 4) ^ ((lane >> 1) & 3)) * 8;
    const int abase = (wm * 128 + (lane & 15)) * 32 + koff;
    const int bbase = (wn * 64  + (lane & 15)) * 32 + koff;

    f32x4 acc[8][4];
#pragma unroll
    for (int i = 0; i < 8; i++)
#pragma unroll
        for (int j = 0; j < 4; j++) acc[i][j] = (f32x4){0.f, 0.f, 0.f, 0.f};

    auto stage = [&](int bb, int kt) {
#pragma unroll
        for (int i = 0; i < 2; i++) {
            glds16(Ahi + gA[i] + kt, &lds[bb][0][seg[i]]);
            glds16(Alo + gA[i] + kt, &lds[bb][1][seg[i]]);
            glds16(Bhi + gB[i] + kt, &lds[bb][2][seg[i]]);
            glds16(Blo + gB[i] + kt, &lds[bb][3][seg[i]]);
        }
    };

    stage(0, 0);
    __syncthreads();

    const int nt = K / 32;
    for (int t = 0; t < nt; t++) {
        const int cur = t & 1;
        if (t + 1 < nt) stage(cur ^ 1, (t + 1) * 32);

        bf16x8 bhf[4], blf[4];
#pragma unroll
        for (int fn = 0; fn < 4; fn++) {
            bhf[fn] = *(const bf16x8*)&lds[cur][2][bbase + fn * 512];
            blf[fn] = *(const bf16x8*)&lds[cur][3][bbase + fn * 512];
        }
#pragma unroll
        for (int half = 0; half < 2; half++) {
            bf16x8 ahf[4], alf[4];
#pragma unroll
            for (int i = 0; i < 4; i++) {
                ahf[i] = *(const bf16x8*)&lds[cur][0][abase + (half * 4 + i) * 512];
                alf[i] = *(const bf16x8*)&lds[cur][1][abase + (half * 4 + i) * 512];
            }
#pragma unroll
            for (int i = 0; i < 4; i++)
#pragma unroll
                for (int fn = 0; fn < 4; fn++) {
                    f32x4 a = acc[half * 4 + i][fn];
                    a = __builtin_amdgcn_mfma_f32_16x16x32_bf16(ahf[i], bhf[fn], a, 0, 0, 0);
                    a = __builtin_amdgcn_mfma_f32_16x16x32_bf16(ahf[i], blf[fn], a, 0, 0, 0);
                    a = __builtin_amdgcn_mfma_f32_16x16x32_bf16(alf[i], bhf[fn], a, 0, 0, 0);
                    acc[half * 4 + i][fn] = a;
                }
        }
        __syncthreads();
    }

    // epilogue: C/D layout col = lane&15, row = (lane>>4)*4 + e
    const int rb = bm + wm * 128;
    const int cb = bn + wn * 64;
    const float* bp = bias;
    int cbb = cb;
    if (cb >= nsplit) { bp = bias2; cbb = cb - nsplit; }   // wave-uniform
    float bv[4];
#pragma unroll
    for (int fn = 0; fn < 4; fn++) bv[fn] = bp[cbb + fn * 16 + (lane & 15)];
#pragma unroll
    for (int fm = 0; fm < 8; fm++)
#pragma unroll
        for (int e = 0; e < 4; e++) {
            size_t row = (size_t)(rb + fm * 16 + (lane >> 4) * 4 + e);
            if constexpr (SPLIT) {
#pragma unroll
                for (int fn = 0; fn < 4; fn++) {
                    float v = acc[fm][fn][e] + bv[fn];
                    unsigned short h = bf16_rtne(v);
                    Chi[row * N + cb + fn * 16 + (lane & 15)] = h;
                    Clo[row * N + cb + fn * 16 + (lane & 15)] = bf16_rtne(v - bf16_to_f32(h));
                }
            } else {
                float* cp = &C[row * N];
#pragma unroll
                for (int fn = 0; fn < 4; fn++)
                    cp[cb + fn * 16 + (lane & 15)] = acc[fm][fn][e] + bv[fn];
            }
        }
}

// ---------------------------------------------------------------------------
// Bin assignment + soft aggregation (MFMA aggregation, r6 structure).
// Kbuf/Vbuf may point into one fused [M][ld] buffer (V = base + 1024).
// ---------------------------------------------------------------------------
__global__ __launch_bounds__(256)
void bin_assign_agg(const float* __restrict__ Kbuf, const float* __restrict__ Vbuf,
                    int ld,
                    const float* __restrict__ W_bin, const float* __restrict__ proto,
                    const float* __restrict__ log_tau,
                    float* __restrict__ partials, int B, int S)
{
    __shared__ __attribute__((aligned(16))) float Wb[8][64];
    __shared__ __attribute__((aligned(16))) float Prt[8][64];
    __shared__ __attribute__((aligned(16))) float zsm[64][8];
    __shared__ __attribute__((aligned(16))) float Kt[64][68];
    __shared__ __attribute__((aligned(16))) u32 KT32[64][68];   // [d][s] packed hi|lo
    __shared__ __attribute__((aligned(16))) u32 VT32[64][68];
    __shared__ __attribute__((aligned(16))) u32 P32T[64][68];   // [n][s] packed hi|lo

    const int bh = blockIdx.x;
    const int h  = bh & (N_HEADS - 1);
    const int b  = bh >> 4;
    const int chunk = blockIdx.y;
    const int CH = gridDim.y;
    const int tid = threadIdx.x;
    const int lane = tid & 63;
    const int w = tid >> 6;

    if (tid < 128) {
        ((f4*)&Wb[0][0])[tid] = ((const f4*)W_bin)[tid];
    } else {
        int t = tid - 128;
        f4 p = ((const f4*)(proto + (size_t)h * N_BINS * D_LAT))[t];
        int n = t >> 1, l4 = (t & 1) * 4;
        Prt[l4 + 0][n] = p[0];
        Prt[l4 + 1][n] = p[1];
        Prt[l4 + 2][n] = p[2];
        Prt[l4 + 3][n] = p[3];
    }
    const float tau   = fmaxf(expf(log_tau[h]), 1e-3f);
    const float scale = 1.0f / (tau + 1e-8f);

    const int row = tid >> 2, sub = tid & 3;   // softmax: 4 lanes per key row
    const int lr = lane & 15, lc = lane >> 4;  // MFMA fragment indices
    const int mat = w >> 1;                    // 0 = K, 1 = V
    const int fn0 = (w & 1) * 2;               // d fragment pair

    f32x4 acc[4][2];
    f4 cntv[4];
#pragma unroll
    for (int i = 0; i < 4; i++) {
        cntv[i] = (f4){0.f, 0.f, 0.f, 0.f};
        acc[i][0] = (f32x4){0.f, 0.f, 0.f, 0.f};
        acc[i][1] = (f32x4){0.f, 0.f, 0.f, 0.f};
    }

    const int SC = S / CH;
    const int s_base = chunk * SC;

    for (int s0 = 0; s0 < SC; s0 += 64) {
        __syncthreads();   // previous chunk's MFMA reads done before restage
#pragma unroll
        for (int q = 0; q < 2; q++) {
            int item = tid + 256 * q;       // 0..511
            int rp = item >> 4;             // 0..31
            int dc = item & 15;
            int r0 = rp * 2;
            size_t gi = ((size_t)(b * S + s_base + s0 + r0)) * ld + h * D_HEAD + dc * 4;
            f4 k0 = *(const f4*)&Kbuf[gi];
            f4 k1 = *(const f4*)&Kbuf[gi + ld];
            f4 v0 = *(const f4*)&Vbuf[gi];
            f4 v1 = *(const f4*)&Vbuf[gi + ld];
            *(f4*)&Kt[r0][dc * 4]     = k0;
            *(f4*)&Kt[r0 + 1][dc * 4] = k1;
#pragma unroll
            for (int j = 0; j < 4; j++) {
                int d = dc * 4 + j;
                *(u32x2*)&KT32[d][r0] = (u32x2){pack_hl(k0[j]), pack_hl(k1[j])};
                *(u32x2*)&VT32[d][r0] = (u32x2){pack_hl(v0[j]), pack_hl(v1[j])};
            }
        }
        __syncthreads();

        {
            const int l0 = sub * 2;
            f4 z0 = {0.f, 0.f, 0.f, 0.f}, z1 = {0.f, 0.f, 0.f, 0.f};
#pragma unroll
            for (int d4 = 0; d4 < 16; d4++) {
                f4 kv = *(const f4*)&Kt[row][d4 * 4];
                f4 w0 = *(const f4*)&Wb[l0][d4 * 4];
                f4 w1 = *(const f4*)&Wb[l0 + 1][d4 * 4];
                z0 += kv * w0;
                z1 += kv * w1;
            }
            zsm[row][l0]     = z0[0] + z0[1] + z0[2] + z0[3];
            zsm[row][l0 + 1] = z1[0] + z1[1] + z1[2] + z1[3];
        }
        __syncthreads();

        {
            float zr[8];
#pragma unroll
            for (int l = 0; l < 8; l++) zr[l] = zsm[row][l];
            f4 lg[4];
#pragma unroll
            for (int q = 0; q < 4; q++) lg[q] = (f4){0.f, 0.f, 0.f, 0.f};
#pragma unroll
            for (int l = 0; l < 8; l++) {
                float zv = zr[l];
#pragma unroll
                for (int q = 0; q < 4; q++) {
                    f4 pr = *(const f4*)&Prt[l][sub * 16 + q * 4];
                    lg[q] += zv * pr;
                }
            }
            float mx = -1e30f;
#pragma unroll
            for (int q = 0; q < 4; q++) {
                lg[q] *= scale;
                mx = fmaxf(mx, fmaxf(fmaxf(lg[q][0], lg[q][1]), fmaxf(lg[q][2], lg[q][3])));
            }
            mx = fmaxf(mx, __shfl_xor(mx, 1));
            mx = fmaxf(mx, __shfl_xor(mx, 2));
            float sum = 0.f;
            f4 pv[4];
#pragma unroll
            for (int q = 0; q < 4; q++) {
#pragma unroll
                for (int e = 0; e < 4; e++) {
                    float ev = expf(lg[q][e] - mx);
                    pv[q][e] = ev;
                    sum += ev;
                }
            }
            sum += __shfl_xor(sum, 1);
            sum += __shfl_xor(sum, 2);
            float inv = 1.0f / sum;
#pragma unroll
            for (int q = 0; q < 4; q++) {
                pv[q] *= inv;
                cntv[q] += pv[q];
#pragma unroll
                for (int e = 0; e < 4; e++)
                    P32T[sub * 16 + q * 4 + e][row] = pack_hl(pv[q][e]);
            }
        }
        __syncthreads();

#pragma unroll
        for (int ks = 0; ks < 2; ks++) {
            bf16x8 pah[4], pal[4];
#pragma unroll
            for (int fm = 0; fm < 4; fm++)
                unpack8(&P32T[fm * 16 + lr][ks * 32 + lc * 8], pah[fm], pal[fm]);
#pragma unroll
            for (int fnL = 0; fnL < 2; fnL++) {
                int dr = (fn0 + fnL) * 16 + lr;
                bf16x8 bhf, blf;
                const u32* bp = mat ? &VT32[dr][ks * 32 + lc * 8]
                                    : &KT32[dr][ks * 32 + lc * 8];
                unpack8(bp, bhf, blf);
#pragma unroll
                for (int fm = 0; fm < 4; fm++) {
                    f32x4 a = acc[fm][fnL];
                    a = __builtin_amdgcn_mfma_f32_16x16x32_bf16(pah[fm], bhf, a, 0, 0, 0);
                    a = __builtin_amdgcn_mfma_f32_16x16x32_bf16(pah[fm], blf, a, 0, 0, 0);
                    a = __builtin_amdgcn_mfma_f32_16x16x32_bf16(pal[fm], bhf, a, 0, 0, 0);
                    acc[fm][fnL] = a;
                }
            }
        }
    }

#pragma unroll
    for (int q = 0; q < 4; q++)
#pragma unroll
        for (int e = 0; e < 4; e++) {
            float c = cntv[q][e];
            c += __shfl_xor(c, 4);
            c += __shfl_xor(c, 8);
            c += __shfl_xor(c, 16);
            c += __shfl_xor(c, 32);
            cntv[q][e] = c;
        }

    float* base = partials + ((size_t)bh * CH + chunk) * 8448;
#pragma unroll
    for (int fm = 0; fm < 4; fm++)
#pragma unroll
        for (int fnL = 0; fnL < 2; fnL++)
#pragma unroll
            for (int e = 0; e < 4; e++) {
                int n = fm * 16 + lc * 4 + e;
                int d = (fn0 + fnL) * 16 + lr;
                base[mat * 4096 + (size_t)n * 64 + d] = acc[fm][fnL][e];
            }
    if ((lane >> 2) == 0) {   // lanes 0..3, sub = lane
#pragma unroll
        for (int q = 0; q < 4; q++)
#pragma unroll
            for (int e = 0; e < 4; e++)
                base[8192 + w * 64 + sub * 16 + q * 4 + e] = cntv[q][e];
    }
}

// ---------------------------------------------------------------------------
// Reduce partials -> bf16 hi/lo K_binned [bh][n][d] and V_binned^T [bh][d][n].
// FAITHFUL to reference broadcast bug: feature d divided by counts[d].
// ---------------------------------------------------------------------------
__global__ __launch_bounds__(256)
void bin_reduce(const float* __restrict__ partials,
                u16* __restrict__ Kbh, u16* __restrict__ Kbl,
                u16* __restrict__ Vth, u16* __restrict__ Vtl, int CH)
{
    const int bh = blockIdx.x;
    const int tid = threadIdx.x;
    __shared__ float inv_cnt[64];
    const float* base = partials + (size_t)bh * CH * 8448;
    if (tid < 64) {
        float c = 0.f;
        for (int ch = 0; ch < CH; ch++)
#pragma unroll
            for (int ww = 0; ww < 4; ww++)
                c += base[(size_t)ch * 8448 + 8192 + ww * 64 + tid];
        inv_cnt[tid] = 1.0f / (c + 1e-6f);
    }
    __syncthreads();
    for (int idx = tid; idx < 4096; idx += 256) {
        float k = 0.f, v = 0.f;
        for (int ch = 0; ch < CH; ch++) {
            const float* p = base + (size_t)ch * 8448;
            k += p[idx];
            v += p[4096 + idx];
        }
        float ic = inv_cnt[idx & 63];   // divide by count of FEATURE index d
        k *= ic;
        v *= ic;
        int n = idx >> 6, d = idx & 63;
        u16 kh = bf16_rtne(k);
        Kbh[(size_t)bh * 4096 + idx] = kh;
        Kbl[(size_t)bh * 4096 + idx] = bf16_rtne(k - bf16_to_f32(kh));
        u16 vh = bf16_rtne(v);
        size_t ti = (size_t)bh * 4096 + (size_t)d * 64 + n;   // transposed
        Vth[ti] = vh;
        Vtl[ti] = bf16_rtne(v - bf16_to_f32(vh));
    }
}

// ---------------------------------------------------------------------------
// Bin attention via bf16x2 MFMA (unchanged, passing).
// ---------------------------------------------------------------------------
__global__ __launch_bounds__(256)
void bin_attn_mfma(const u16* __restrict__ Qhi, const u16* __restrict__ Qlo,
                   const u16* __restrict__ Kbh, const u16* __restrict__ Kbl,
                   const u16* __restrict__ Vth, const u16* __restrict__ Vtl,
                   u16* __restrict__ ctx_hi, u16* __restrict__ ctx_lo,
                   int B, int S)
{
    __shared__ unsigned int P32[4][64][68];

    const int bh = blockIdx.x;
    const int h  = bh & (N_HEADS - 1);
    const int b  = bh >> 4;
    const int tid = threadIdx.x;
    const int l  = tid & 63;
    const int w  = tid >> 6;
    const int s0 = blockIdx.y * 256 + w * 64;

    const int lr = l & 15;
    const int lc = l >> 4;

    const size_t qoff  = ((size_t)(b * S + s0 + lr)) * D_MODEL + h * D_HEAD + lc * 8;
    const size_t kboff = (size_t)bh * 4096 + (size_t)lr * 64 + lc * 8;

    f32x4 acc[4][4];
#pragma unroll
    for (int i = 0; i < 4; i++)
#pragma unroll
        for (int j = 0; j < 4; j++) acc[i][j] = (f32x4){0.f, 0.f, 0.f, 0.f};

#pragma unroll
    for (int ks = 0; ks < 2; ks++) {
        bf16x8 qh[4], ql[4], kh[4], kl[4];
#pragma unroll
        for (int f = 0; f < 4; f++) {
            qh[f] = *(const bf16x8*)(Qhi + qoff + f * 16 * D_MODEL + ks * 32);
            ql[f] = *(const bf16x8*)(Qlo + qoff + f * 16 * D_MODEL + ks * 32);
            kh[f] = *(const bf16x8*)(Kbh + kboff + f * 1024 + ks * 32);
            kl[f] = *(const bf16x8*)(Kbl + kboff + f * 1024 + ks * 32);
        }
#pragma unroll
        for (int fm = 0; fm < 4; fm++)
#pragma unroll
            for (int fn = 0; fn < 4; fn++) {
                acc[fm][fn] = __builtin_amdgcn_mfma_f32_16x16x32_bf16(qh[fm], kh[fn], acc[fm][fn], 0, 0, 0);
                acc[fm][fn] = __builtin_amdgcn_mfma_f32_16x16x32_bf16(qh[fm], kl[fn], acc[fm][fn], 0, 0, 0);
                acc[fm][fn] = __builtin_amdgcn_mfma_f32_16x16x32_bf16(ql[fm], kh[fn], acc[fm][fn], 0, 0, 0);
            }
    }

#pragma unroll
    for (int fm = 0; fm < 4; fm++) {
#pragma unroll
        for (int e = 0; e < 4; e++) {
            float v0 = acc[fm][0][e] * 0.125f;
            float v1 = acc[fm][1][e] * 0.125f;
            float v2 = acc[fm][2][e] * 0.125f;
            float v3 = acc[fm][3][e] * 0.125f;
            float mx = fmaxf(fmaxf(v0, v1), fmaxf(v2, v3));
            mx = fmaxf(mx, __shfl_xor(mx, 1));
            mx = fmaxf(mx, __shfl_xor(mx, 2));
            mx = fmaxf(mx, __shfl_xor(mx, 4));
            mx = fmaxf(mx, __shfl_xor(mx, 8));
            float e0 = expf(v0 - mx), e1 = expf(v1 - mx);
            float e2 = expf(v2 - mx), e3 = expf(v3 - mx);
            float sum = e0 + e1 + e2 + e3;
            sum += __shfl_xor(sum, 1);
            sum += __shfl_xor(sum, 2);
            sum += __shfl_xor(sum, 4);
            sum += __shfl_xor(sum, 8);
            float inv = 1.0f / sum;
            float pv[4] = {e0 * inv, e1 * inv, e2 * inv, e3 * inv};
            int rowi = fm * 16 + lc * 4 + e;
#pragma unroll
            for (int fn = 0; fn < 4; fn++)
                P32[w][rowi][fn * 16 + lr] = pack_hl(pv[fn]);
        }
    }
    // only intra-wave LDS dependency (each wave owns P32[w])

    f32x4 acc2[4][4];
#pragma unroll
    for (int i = 0; i < 4; i++)
#pragma unroll
        for (int j = 0; j < 4; j++) acc2[i][j] = (f32x4){0.f, 0.f, 0.f, 0.f};

#pragma unroll
    for (int ks = 0; ks < 2; ks++) {
        bf16x8 vh[4], vl[4];
#pragma unroll
        for (int f = 0; f < 4; f++) {
            vh[f] = *(const bf16x8*)(Vth + kboff + f * 1024 + ks * 32);
            vl[f] = *(const bf16x8*)(Vtl + kboff + f * 1024 + ks * 32);
        }
        bf16x8 ph[4], pl[4];
#pragma unroll
        for (int fm = 0; fm < 4; fm++)
            unpack8(&P32[w][fm * 16 + lr][ks * 32 + lc * 8], ph[fm], pl[fm]);
#pragma unroll
        for (int fm = 0; fm < 4; fm++)
#pragma unroll
            for (int fn = 0; fn < 4; fn++) {
                acc2[fm][fn] = __builtin_amdgcn_mfma_f32_16x16x32_bf16(ph[fm], vh[fn], acc2[fm][fn], 0, 0, 0);
                acc2[fm][fn] = __builtin_amdgcn_mfma_f32_16x16x32_bf16(ph[fm], vl[fn], acc2[fm][fn], 0, 0, 0);
                acc2[fm][fn] = __builtin_amdgcn_mfma_f32_16x16x32_bf16(pl[fm], vh[fn], acc2[fm][fn], 0, 0, 0);
            }
    }

    const size_t gbase = ((size_t)(b * S + s0 + lc * 4)) * D_MODEL + h * D_HEAD + lr;
#pragma unroll
    for (int fm = 0; fm < 4; fm++)
#pragma unroll
        for (int e = 0; e < 4; e++) {
            size_t ro = gbase + ((size_t)(fm * 16 + e)) * D_MODEL;
#pragma unroll
            for (int fn = 0; fn < 4; fn++) {
                float v = acc2[fm][fn][e];
                u16 hv = bf16_rtne(v);
                ctx_hi[ro + fn * 16] = hv;
                ctx_lo[ro + fn * 16] = bf16_rtne(v - bf16_to_f32(hv));
            }
        }
}

// ---------------------------------------------------------------------------
extern "C" void kernel_launch(void* const* d_in, const int* in_sizes, int n_in,
                              void* d_out, int out_size, void* d_ws, size_t ws_size,
                              hipStream_t stream)
{
    (void)n_in; (void)out_size; (void)ws_size;
    const float* x       = (const float*)d_in[0];
    const float* Wq      = (const float*)d_in[1];
    const float* bq      = (const float*)d_in[2];
    const float* Wk      = (const float*)d_in[3];
    const float* bk      = (const float*)d_in[4];
    const float* Wv      = (const float*)d_in[5];
    const float* bv      = (const float*)d_in[6];
    const float* Wo      = (const float*)d_in[7];
    const float* bo      = (const float*)d_in[8];
    const float* W_bin   = (const float*)d_in[9];
    const float* proto   = (const float*)d_in[10];
    const float* log_tau = (const float*)d_in[11];
    float* out = (float*)d_out;

    const int M  = in_sizes[0] / D_MODEL;   // B*S = 16384
    const int S  = 4096;
    const int B  = M / S;                   // 4
    const int BH = B * N_HEADS;             // 64
    const int CH = 8;

    const size_t MB = (size_t)1 << 20;
    char* wsb = (char*)d_ws;
    float*          KV   = (float*)wsb;                        // 128 MB: fused [M][2048] K|V
    unsigned short* XShi = (unsigned short*)(wsb + 128 * MB);  // 32 MB: x_hi -> ctx_hi
    unsigned short* XSlo = (unsigned short*)(wsb + 160 * MB);  // 32 MB: x_lo -> ctx_lo
    unsigned short* W4hi = (unsigned short*)(wsb + 192 * MB);  //  8 MB: q,k,v,o concat
    unsigned short* W4lo = (unsigned short*)(wsb + 200 * MB);  //  8 MB
    u16*            Kbh  = (u16*)(wsb + 208 * MB);             // 512 KB each
    u16*            Kbl  = Kbh + (size_t)BH * 4096;
    u16*            Vth  = Kbl + (size_t)BH * 4096;
    u16*            Vtl  = Vth + (size_t)BH * 4096;

    // partials (17.3 MB @ CH=8) scratch lives in d_out (67 MB): fully written
    // by bin_assign_agg, consumed by bin_reduce, then overwritten by final GEMM.
    float* part = (float*)d_out;

    u16* Qhi = (u16*)KV;                       // Q hi/lo overlay KV (dead after bin_assign)
    u16* Qlo = Qhi + (size_t)M * D_MODEL;

    const size_t WOFF = (size_t)D_MODEL * D_MODEL;   // per-weight offset in concat
    const int n8x = (M * D_MODEL) / 8;
    const int n8w = (D_MODEL * D_MODEL) / 8;
    dim3 gg(M / 256, D_MODEL / 256);           // (64, 4) for N=1024
    dim3 gg2(M / 256, 2 * D_MODEL / 256);      // (64, 8) for fused N=2048

    split_bf16x2<<<n8x / 256, 256, 0, stream>>>(x, XShi, XSlo, n8x);
    split4_w<<<dim3(n8w / 256, 4), 256, 0, stream>>>(Wq, Wk, Wv, Wo, W4hi, W4lo);

    // fused K|V projection: B = [Wk; Wv] (contiguous in the q,k,v,o concat),
    // N = 2048, bias split at column 1024.
    gemm_bf16x2_nt<false><<<gg2, 512, 0, stream>>>(XShi, XSlo, W4hi + WOFF, W4lo + WOFF,
                                                   bk, bv, 1024, KV, nullptr, nullptr,
                                                   M, 2 * D_MODEL, D_MODEL);

    bin_assign_agg<<<dim3(BH, CH), 256, 0, stream>>>(KV, KV + D_MODEL, 2 * D_MODEL,
                                                     W_bin, proto, log_tau, part, B, S);
    bin_reduce<<<BH, 256, 0, stream>>>(part, Kbh, Kbl, Vth, Vtl, CH);

    // Q projection writes bf16 hi/lo directly (KV fp32 consumed above)
    gemm_bf16x2_nt<true><<<gg, 512, 0, stream>>>(XShi, XSlo, W4hi, W4lo,
                                                 bq, bq, D_MODEL, nullptr, Qhi, Qlo,
                                                 M, D_MODEL, D_MODEL);

    // ctx hi/lo overwrite XShi/XSlo (x splits dead after Q GEMM)
    bin_attn_mfma<<<dim3(BH, S / 256), 256, 0, stream>>>(Qhi, Qlo, Kbh, Kbl, Vth, Vtl,
                                                         XShi, XSlo, B, S);

    gemm_bf16x2_nt<false><<<gg, 512, 0, stream>>>(XShi, XSlo, W4hi + 3 * WOFF, W4lo + 3 * WOFF,
                                                  bo, bo, D_MODEL, out, nullptr, nullptr,
                                                  M, D_MODEL, D_MODEL);
}